// Round 14
// baseline (348.812 us; speedup 1.0000x reference)
//
#include <hip/hip_runtime.h>
#include <stdint.h>

#define NB 64
#define NH 32
#define KCTX 4096
#define HID 7168
#define QLORA 1536
#define KVL 512
#define DTOT 576
#define NSPLIT 4
#define KSPAN 1024
#define NTILE 64           // KSPAN/16
#define TK 16
#define SM_SCALE 0.07216878364870323f  // 1/sqrt(192)
#define NEGINF (-3.0e38f)

typedef __attribute__((ext_vector_type(4))) float f32x4;
typedef __attribute__((ext_vector_type(8))) __bf16 bf16x8;

#define LGKM_BARRIER() do{ asm volatile("s_waitcnt lgkmcnt(0)" ::: "memory"); __builtin_amdgcn_s_barrier(); } while(0)

static __device__ __forceinline__ void glds16(const void* g, void* s){
    __builtin_amdgcn_global_load_lds((const __attribute__((address_space(1))) void*)g,
                                     (__attribute__((address_space(3))) void*)s, 16, 0, 0);
}

static __device__ __forceinline__ unsigned short f2bf(float f){
    union{__bf16 h; unsigned short s;} x; x.h = (__bf16)f; return x.s;
}
static __device__ __forceinline__ float bf2f(unsigned short h){
    union{unsigned i;float f;}x; x.i=((unsigned)h)<<16; return x.f;
}
static __device__ __forceinline__ unsigned pack2(float a, float b){
    union{__bf16 h[2]; unsigned u;} x; x.h[0]=(__bf16)a; x.h[1]=(__bf16)b; return x.u;
}

// ================= GEMM cores =================
// v3 packed core: glds16 triple-buffered staging, counted vmcnt(4), 1 barrier/k-step.
// LDS A layout identity with packed source: word kb*64+m (per k-step window).
// LDS W layout [32 k][64 n] fp32 row-major; cvt to bf16 hi/lo at fragment read.
// OUT_MODE: 0 = write partials P[s][m][n]; 1 = unsafeAtomicAdd into Out[m][n]
template<int OUT_MODE>
static __device__ __forceinline__ void gemm_core_packed(
        const unsigned short* __restrict__ Ahi, const unsigned short* __restrict__ Alo,
        const float* __restrict__ Wm, float* __restrict__ P, int N, int ksteps,
        int bx, int by,
        unsigned short* Ah3, unsigned short* Al3, float* Wf3)
{
    const int tid = threadIdx.x;
    const int w = tid>>6, l = tid&63, lm = l&15, lg = l>>4;
    const int n0 = bx*64;
    const int s  = by;

    f32x4 acc[4];
#pragma unroll
    for (int i=0;i<4;++i){ acc[i][0]=0.f; acc[i][1]=0.f; acc[i][2]=0.f; acc[i][3]=0.f; }

    auto issue_tile = [&](int t, int buf){
        const int k0g = (s*ksteps + t)*32;
        // A hi/lo: LDS word c = tid = kb*64+m (kb=w, m=l); source word ((k0>>3)+kb)*64+m
        size_t ga = (size_t)((k0g>>3) + w)*64 + l;
        glds16(Ahi + ga*8, Ah3 + buf*2048 + tid*8);
        glds16(Alo + ga*8, Al3 + buf*2048 + tid*8);
        // W tile: chunk c -> row r=c>>4, cols (c&15)*4..+3
#pragma unroll
        for (int i=0;i<2;++i){
            int c = tid + i*256;
            int r = c>>4, c4 = (c&15)<<2;
            glds16(Wm + (size_t)(k0g+r)*N + n0 + c4, Wf3 + buf*2048 + c*4);
        }
    };

    issue_tile(0, 0);
    if (ksteps > 1) issue_tile(1, 1);
    asm volatile("s_waitcnt vmcnt(4)" ::: "memory");   // tile 0 landed (4 glds16/tile/wave)
    __builtin_amdgcn_s_barrier();

    int cur = 0;
    for (int t=0; t<ksteps; ++t){
        if (t+2 < ksteps){
            int ib = cur+2; if (ib>=3) ib-=3;
            issue_tile(t+2, ib);                        // 2 tiles in flight
        }
        const unsigned short* Ahb = Ah3 + cur*2048;
        const unsigned short* Alb = Al3 + cur*2048;
        const float* Wb = Wf3 + cur*2048;
        const int fa = (lg*64 + w*16 + lm)*8;           // A[kb=lg][m=w*16+lm]
        bf16x8 fah = *(const bf16x8*)(Ahb + fa);
        bf16x8 fal = *(const bf16x8*)(Alb + fa);
#pragma unroll
        for (int nt=0;nt<4;++nt){
            const float* wb = Wb + lg*512 + nt*16 + lm; // W[k=lg*8+j][n=nt*16+lm]
            float wv[8];
#pragma unroll
            for (int j=0;j<8;++j) wv[j] = wb[(size_t)j*64];
            unsigned short hb8[8], lb8[8];
#pragma unroll
            for (int j=0;j<8;++j){
                hb8[j] = f2bf(wv[j]);
                lb8[j] = f2bf(wv[j] - bf2f(hb8[j]));
            }
            union{uint4 u; bf16x8 v;} fbh, fbl;
            fbh.u.x=(unsigned)hb8[0]|((unsigned)hb8[1]<<16); fbh.u.y=(unsigned)hb8[2]|((unsigned)hb8[3]<<16);
            fbh.u.z=(unsigned)hb8[4]|((unsigned)hb8[5]<<16); fbh.u.w=(unsigned)hb8[6]|((unsigned)hb8[7]<<16);
            fbl.u.x=(unsigned)lb8[0]|((unsigned)lb8[1]<<16); fbl.u.y=(unsigned)lb8[2]|((unsigned)lb8[3]<<16);
            fbl.u.z=(unsigned)lb8[4]|((unsigned)lb8[5]<<16); fbl.u.w=(unsigned)lb8[6]|((unsigned)lb8[7]<<16);
            acc[nt] = __builtin_amdgcn_mfma_f32_16x16x32_bf16(fah, fbh.v, acc[nt], 0,0,0);
            acc[nt] = __builtin_amdgcn_mfma_f32_16x16x32_bf16(fal, fbh.v, acc[nt], 0,0,0);
            acc[nt] = __builtin_amdgcn_mfma_f32_16x16x32_bf16(fah, fbl.v, acc[nt], 0,0,0);
        }
        // tail: counted wait (tile t+2 stays in flight); drain only at the end
        if (t+2 < ksteps){
            asm volatile("s_waitcnt vmcnt(4)" ::: "memory");
            __builtin_amdgcn_s_barrier();
        } else if (t+1 < ksteps){
            asm volatile("s_waitcnt vmcnt(0)" ::: "memory");
            __builtin_amdgcn_s_barrier();
        }
        cur = cur+1; if (cur>=3) cur-=3;
    }
#pragma unroll
    for (int nt=0;nt<4;++nt){
        int n = n0 + nt*16 + lm;
#pragma unroll
        for (int r=0;r<4;++r){
            int m = w*16 + lg*4 + r;
            if (OUT_MODE == 0) P[((size_t)s*64 + m)*N + n] = acc[nt][r];
            else               unsafeAtomicAdd(&P[(size_t)m*N + n], acc[nt][r]);
        }
    }
}

// raw fp32 A (A[64][KA] row-major), converted in-register (unchanged r13 core)
static __device__ __forceinline__ void gemm_core_raw(
        const float* __restrict__ Araw, int KA,
        const float* __restrict__ Wm, float* __restrict__ P, int N, int ksteps,
        int bx, int by,
        unsigned short* Ah, unsigned short* Al, unsigned short* Bh, unsigned short* Bl)
{
    const int tid = threadIdx.x;
    const int w = tid>>6, l = tid&63, lm = l&15, lg = l>>4;
    const int n0 = bx*64;
    const int s  = by;
    const int mn = tid&63, ks = tid>>6;
    const int widx = ((mn>>4)*64 + ks*16 + (mn&15));

    f32x4 acc[4];
#pragma unroll
    for (int i=0;i<4;++i){ acc[i][0]=0.f; acc[i][1]=0.f; acc[i][2]=0.f; acc[i][3]=0.f; }

    float av[8], wv[8];
    auto load_raw = [&](int t){
        const int k0 = (s*ksteps + t)*32;
        const float* ap = Araw + (size_t)mn*KA + k0 + ks*8;
        *(float4*)(av)   = *(const float4*)(ap);
        *(float4*)(av+4) = *(const float4*)(ap+4);
        const float* wp = Wm + (size_t)(k0 + ks*8)*N + n0 + mn;
#pragma unroll
        for (int j=0;j<8;++j) wv[j] = wp[(size_t)j*N];
    };
    auto cvt_write = [&](int buf){
        unsigned short ha[8], la[8], hb[8], lb[8];
#pragma unroll
        for (int j=0;j<8;++j){
            ha[j] = f2bf(av[j]); la[j] = f2bf(av[j] - bf2f(ha[j]));
            hb[j] = f2bf(wv[j]); lb[j] = f2bf(wv[j] - bf2f(hb[j]));
        }
        uint4 ah4, al4, bh4, bl4;
        ah4.x=(unsigned)ha[0]|((unsigned)ha[1]<<16); ah4.y=(unsigned)ha[2]|((unsigned)ha[3]<<16);
        ah4.z=(unsigned)ha[4]|((unsigned)ha[5]<<16); ah4.w=(unsigned)ha[6]|((unsigned)ha[7]<<16);
        al4.x=(unsigned)la[0]|((unsigned)la[1]<<16); al4.y=(unsigned)la[2]|((unsigned)la[3]<<16);
        al4.z=(unsigned)la[4]|((unsigned)la[5]<<16); al4.w=(unsigned)la[6]|((unsigned)la[7]<<16);
        bh4.x=(unsigned)hb[0]|((unsigned)hb[1]<<16); bh4.y=(unsigned)hb[2]|((unsigned)hb[3]<<16);
        bh4.z=(unsigned)hb[4]|((unsigned)hb[5]<<16); bh4.w=(unsigned)hb[6]|((unsigned)hb[7]<<16);
        bl4.x=(unsigned)lb[0]|((unsigned)lb[1]<<16); bl4.y=(unsigned)lb[2]|((unsigned)lb[3]<<16);
        bl4.z=(unsigned)lb[4]|((unsigned)lb[5]<<16); bl4.w=(unsigned)lb[6]|((unsigned)lb[7]<<16);
        *(uint4*)(Ah + buf*2048 + widx*8) = ah4;
        *(uint4*)(Al + buf*2048 + widx*8) = al4;
        *(uint4*)(Bh + buf*2048 + widx*8) = bh4;
        *(uint4*)(Bl + buf*2048 + widx*8) = bl4;
    };

    load_raw(0);
    for (int t=0; t<ksteps; ++t){
        const int buf = t&1;
        cvt_write(buf);
        __syncthreads();
        if (t+1 < ksteps) load_raw(t+1);
        const int fa = buf*2048 + (w*64 + lg*16 + lm)*8;
        bf16x8 fah = *(const bf16x8*)(Ah + fa);
        bf16x8 fal = *(const bf16x8*)(Al + fa);
#pragma unroll
        for (int nt=0;nt<4;++nt){
            const int fb = buf*2048 + (nt*64 + lg*16 + lm)*8;
            bf16x8 fbh = *(const bf16x8*)(Bh + fb);
            bf16x8 fbl = *(const bf16x8*)(Bl + fb);
            acc[nt] = __builtin_amdgcn_mfma_f32_16x16x32_bf16(fah, fbh, acc[nt], 0,0,0);
            acc[nt] = __builtin_amdgcn_mfma_f32_16x16x32_bf16(fal, fbh, acc[nt], 0,0,0);
            acc[nt] = __builtin_amdgcn_mfma_f32_16x16x32_bf16(fah, fbl, acc[nt], 0,0,0);
        }
        __syncthreads();
    }
#pragma unroll
    for (int nt=0;nt<4;++nt){
        int n = n0 + nt*16 + lm;
#pragma unroll
        for (int r=0;r<4;++r){
            int m = w*16 + lg*4 + r;
            P[((size_t)s*64 + m)*N + n] = acc[nt][r];
        }
    }
}

__global__ __launch_bounds__(256) void gemm_mfma(
        const unsigned short* __restrict__ Ahi, const unsigned short* __restrict__ Alo,
        const float* __restrict__ Wm, float* __restrict__ P, int N, int ksteps)
{
    __shared__ unsigned short Ah3[3*2048], Al3[3*2048];
    __shared__ float Wf3[3*2048];
    gemm_core_packed<0>(Ahi, Alo, Wm, P, N, ksteps, blockIdx.x, blockIdx.y, Ah3, Al3, Wf3);
}

__global__ __launch_bounds__(256) void gemm_atomic(
        const unsigned short* __restrict__ Ahi, const unsigned short* __restrict__ Alo,
        const float* __restrict__ Wm, float* __restrict__ Out, int N, int ksteps)
{
    __shared__ unsigned short Ah3[3*2048], Al3[3*2048];
    __shared__ float Wf3[3*2048];
    gemm_core_packed<1>(Ahi, Alo, Wm, Out, N, ksteps, blockIdx.x, blockIdx.y, Ah3, Al3, Wf3);
}

// two independent raw-A GEMMs in one launch (hidden @ w_q_a || hidden @ w_kv_a)
__global__ __launch_bounds__(256) void gemm_dual_raw(
        const float* __restrict__ Araw, int KA,
        const float* __restrict__ W0, float* __restrict__ P0, int N0, int ks0, int nbx0, int nblk0,
        const float* __restrict__ W1, float* __restrict__ P1, int N1, int ks1, int nbx1)
{
    __shared__ unsigned short Ah[2*2048], Al[2*2048], Bh[2*2048], Bl[2*2048];
    int bid = blockIdx.x;
    if (bid < nblk0){
        gemm_core_raw(Araw, KA, W0, P0, N0, ks0, bid%nbx0, bid/nbx0, Ah, Al, Bh, Bl);
    } else {
        bid -= nblk0;
        gemm_core_raw(Araw, KA, W1, P1, N1, ks1, bid%nbx1, bid/nbx1, Ah, Al, Bh, Bl);
    }
}

// ================= norms =================
static __device__ __forceinline__ void rms_core(const float* __restrict__ P,
        const float* __restrict__ w, unsigned short* __restrict__ Hi,
        unsigned short* __restrict__ Lo, int S, int b, float* red)
{
    const int t = threadIdx.x;
    float v[6]; float ss = 0.f;
#pragma unroll
    for (int j=0;j<6;++j){
        int n = j*256 + t;
        float s = 0.f;
        for (int sp=0; sp<S; ++sp) s += P[((size_t)sp*64+b)*1536 + n];
        v[j] = s; ss += s*s;
    }
#pragma unroll
    for (int off=32; off>=1; off>>=1) ss += __shfl_xor(ss, off, 64);
    if ((t&63)==0) red[t>>6] = ss;
    __syncthreads();
    float tot = red[0]+red[1]+red[2]+red[3];
    float rs = rsqrtf(tot/1536.f + 1e-6f);
#pragma unroll
    for (int j=0;j<6;++j){
        int n = j*256+t;
        float val = v[j]*rs*w[n];
        unsigned short hs = f2bf(val);
        unsigned short ls = f2bf(val - bf2f(hs));
        size_t ui = (size_t)(n>>3)*512 + b*8 + (n&7);
        Hi[ui] = hs; Lo[ui] = ls;
    }
}

static __device__ __forceinline__ void kvrope_core(const float* __restrict__ P,
        const float* __restrict__ w, const float* __restrict__ cosb, const float* __restrict__ sinb,
        float* __restrict__ latent, int S, int b, float* vals, float* red)
{
    const int t = threadIdx.x;
    float ss = 0.f;
    for (int j=0;j<3;++j){
        int n = j*256+t;
        if (n < 576){
            float s=0.f;
            for (int sp=0;sp<S;++sp) s += P[((size_t)sp*64+b)*576 + n];
            vals[n]=s;
            if (n<512) ss += s*s;
        }
    }
#pragma unroll
    for (int off=32; off>=1; off>>=1) ss += __shfl_xor(ss, off, 64);
    if ((t&63)==0) red[t>>6]=ss;
    __syncthreads();
    float tot = red[0]+red[1]+red[2]+red[3];
    float rs = rsqrtf(tot/512.f + 1e-6f);
    for (int j=0;j<3;++j){
        int n = j*256+t;
        if (n<576){
            float o;
            if (n < 512) o = vals[n]*rs*w[n];
            else if (n < 544){ int i=n-512; o = vals[512+2*i]*cosb[b*32+i] - vals[513+2*i]*sinb[b*32+i]; }
            else            { int i=n-544; o = vals[513+2*i]*cosb[b*32+i] + vals[512+2*i]*sinb[b*32+i]; }
            latent[(size_t)b*576 + n] = o;
        }
    }
}

__global__ __launch_bounds__(256) void norm_dual(
        const float* __restrict__ Pq, const float* __restrict__ qw,
        unsigned short* __restrict__ Hi, unsigned short* __restrict__ Lo, int Sq,
        const float* __restrict__ Pkv, const float* __restrict__ kvw,
        const float* __restrict__ cosb, const float* __restrict__ sinb,
        float* __restrict__ latent, int Skv)
{
    __shared__ float vals[576];
    __shared__ float red[4];
    if (blockIdx.x < 64) rms_core(Pq, qw, Hi, Lo, Sq, blockIdx.x, red);
    else                 kvrope_core(Pkv, kvw, cosb, sinb, latent, Skv, blockIdx.x-64, vals, red);
}

// ---------- finish q: reduce partials; nope part -> packed hi/lo A; rope -> query[512..]
__global__ __launch_bounds__(256) void finish_q(const float* __restrict__ P,
        const float* __restrict__ cosb, const float* __restrict__ sinb,
        unsigned short* __restrict__ qh, unsigned short* __restrict__ ql,
        float* __restrict__ query, int S)
{
    int i = blockIdx.x*256 + threadIdx.x;
    int b = i / 6144, n = i - b*6144;
    float s = 0.f;
    for (int sp=0; sp<S; ++sp) s += P[((size_t)sp*64+b)*6144 + n];
    int h = n/192, nl = n - h*192;
    if (nl < 128){
        unsigned short hs = f2bf(s);
        unsigned short ls = f2bf(s - bf2f(hs));
        size_t ui = (size_t)h*8192 + (size_t)(nl>>3)*512 + b*8 + (nl&7);
        qh[ui]=hs; ql[ui]=ls;
    } else {
        int i2 = (nl-128)>>1;
        float other = __shfl_xor(s, 1);
        float c = cosb[b*32+i2], sn = sinb[b*32+i2];
        float* o = query + ((size_t)b*32+h)*576;
        if ((nl&1)==0) o[512+i2] = s*c - other*sn;
        else           o[544+i2] = s*c + other*sn;
    }
}

// ---------- ql_nope via MFMA, packed A
__global__ __launch_bounds__(256) void qlnope_mfma(const unsigned short* __restrict__ qh,
        const unsigned short* __restrict__ ql,
        const float* __restrict__ wukt, float* __restrict__ query)
{
    __shared__ unsigned short Bh[4096], Bl[4096];
    const int h = blockIdx.x, r0 = blockIdx.y*128;
    const int tid = threadIdx.x;
    const int w = tid>>6, l = tid&63, lm = l&15, lg = l>>4;
    f32x4 acc[8];
#pragma unroll
    for (int i=0;i<8;++i){ acc[i][0]=0.f; acc[i][1]=0.f; acc[i][2]=0.f; acc[i][3]=0.f; }

    for (int ck=0; ck<4; ++ck){
        const int k0 = ck*32;
        unsigned short hh[2][8], ll[2][8]; int wid0 = tid*2;
#pragma unroll
        for (int wi=0; wi<2; ++wi){
            int wid = wid0 + wi;
            int ntile = wid>>6, kg = (wid>>4)&3, nl = wid&15;
            int n = r0 + ntile*16 + nl;
            const float* wp = wukt + (size_t)h*65536 + (size_t)(k0+kg*8)*512 + n;
#pragma unroll
            for (int j=0;j<8;++j){
                float v = wp[(size_t)j*512];
                hh[wi][j] = f2bf(v);
                ll[wi][j] = f2bf(v - bf2f(hh[wi][j]));
            }
        }
        __syncthreads();
#pragma unroll
        for (int wi=0; wi<2; ++wi){
            int wid = wid0 + wi;
            uint4 uh, ul;
            uh.x=(unsigned)hh[wi][0]|((unsigned)hh[wi][1]<<16); uh.y=(unsigned)hh[wi][2]|((unsigned)hh[wi][3]<<16);
            uh.z=(unsigned)hh[wi][4]|((unsigned)hh[wi][5]<<16); uh.w=(unsigned)hh[wi][6]|((unsigned)hh[wi][7]<<16);
            ul.x=(unsigned)ll[wi][0]|((unsigned)ll[wi][1]<<16); ul.y=(unsigned)ll[wi][2]|((unsigned)ll[wi][3]<<16);
            ul.z=(unsigned)ll[wi][4]|((unsigned)ll[wi][5]<<16); ul.w=(unsigned)ll[wi][6]|((unsigned)ll[wi][7]<<16);
            *(uint4*)(Bh + wid*8) = uh;
            *(uint4*)(Bl + wid*8) = ul;
        }
        __syncthreads();
        size_t ai = (size_t)h*8192 + (size_t)(ck*4+lg)*512 + (size_t)(w*16+lm)*8;
        union{uint4 u; bf16x8 v;} fh, fl;
        fh.u = *(const uint4*)(qh + ai);
        fl.u = *(const uint4*)(ql + ai);
#pragma unroll
        for (int nt=0;nt<8;++nt){
            const int fb = (nt*64 + lg*16 + lm)*8;
            bf16x8 fbh = *(const bf16x8*)(Bh + fb);
            bf16x8 fbl = *(const bf16x8*)(Bl + fb);
            acc[nt] = __builtin_amdgcn_mfma_f32_16x16x32_bf16(fh.v, fbh, acc[nt], 0,0,0);
            acc[nt] = __builtin_amdgcn_mfma_f32_16x16x32_bf16(fl.v, fbh, acc[nt], 0,0,0);
            acc[nt] = __builtin_amdgcn_mfma_f32_16x16x32_bf16(fh.v, fbl, acc[nt], 0,0,0);
        }
        __syncthreads();
    }
#pragma unroll
    for (int nt=0;nt<8;++nt){
        int r = r0 + nt*16 + lm;
#pragma unroll
        for (int qq=0;qq<4;++qq){
            int bb = w*16 + lg*4 + qq;
            query[((size_t)bb*32 + h)*576 + r] = acc[nt][qq];
        }
    }
}

// Vt flat layout: addr_u16(d,key) = (d>>2)*64 + ((d&3)^((d>>3)&3))*16 + key
static __device__ __forceinline__ int vt_addr(int d, int key){
    return (d>>2)*64 + (((d&3)^((d>>3)&3))<<4) + key;
}

// ---------- flash decode attention v8 (unchanged from round 13)
__global__ __launch_bounds__(512,1) void attn_mfma(const float* __restrict__ query,
        const float* __restrict__ kv, const float* __restrict__ latent,
        const int* __restrict__ slots, const int* __restrict__ seq_lens,
        float* __restrict__ Opart, float* __restrict__ Mpart, float* __restrict__ Lpart)
{
    __shared__ float Kf[3][16*576];
    __shared__ unsigned short Vt[8192];
    __shared__ float S_s[8][32][16];
    __shared__ unsigned short P_s[32][40];
    __shared__ float alpha_s[32];

    const int b = blockIdx.y, sp = blockIdx.x;
    const int tid = threadIdx.x;
    const int w = tid>>6, l = tid&63;
    const int lm = l&15, lg = l>>4;
    const int ht = w&1;
    const int dg = w>>1;
    const int cs = 2*w + (w>=1?1:0) + (w>=5?1:0);
    const int cnt = ((w&3)==0)?3:2;
    const int seqlen = seq_lens[b];
    const int slot = slots[b];
    const int k0 = sp*KSPAN;
    const int myh = tid>>4, s5 = tid&15;

    P_s[tid>>4][16 + (tid&15)] = 0;

    bf16x8 qf[2][3];
#pragma unroll
    for (int h2=0; h2<2; ++h2){
        const float* qrow = query + ((size_t)b*32 + h2*16 + lm)*576;
#pragma unroll
        for (int ss=0;ss<3;++ss){
            union{uint4 u; bf16x8 v;} cv;
            if (ss < cnt){
                int d0 = (cs+ss)*32 + lg*8;
                float4 a = *(const float4*)(qrow + d0);
                float4 c = *(const float4*)(qrow + d0 + 4);
                cv.u.x=pack2(a.x,a.y); cv.u.y=pack2(a.z,a.w);
                cv.u.z=pack2(c.x,c.y); cv.u.w=pack2(c.z,c.w);
            } else {
                cv.u.x=0; cv.u.y=0; cv.u.z=0; cv.u.w=0;
            }
            qf[h2][ss]=cv.v;
        }
    }

    auto issue_tile = [&](int tt, int buf){
        const int gkb = k0 + tt*TK;
#pragma unroll
        for (int i=0;i<5;++i){
            int s = i*8 + w;
            if (s < 36){
                int B = s*1024 + l*16;
                int r = B / 2304;
                int gs = (B - r*2304) >> 4;
                int g  = gs ^ (r&7);
                int gk = gkb + r; if (gk > KCTX-1) gk = KCTX-1;
                const float* src = (gk==slot) ? (latent + (size_t)b*576 + g*4)
                                              : (kv + ((size_t)b*KCTX + gk)*576 + g*4);
                glds16(src, ((char*)&Kf[buf][0]) + B);
            }
        }
    };

    f32x4 oacc[8];
#pragma unroll
    for (int i=0;i<8;++i){ oacc[i][0]=0.f; oacc[i][1]=0.f; oacc[i][2]=0.f; oacc[i][3]=0.f; }
    float m_run = NEGINF, l_run = 0.f;

    issue_tile(0, 0);
    issue_tile(1, 1);
    if (w < 4) { asm volatile("s_waitcnt vmcnt(5)" ::: "memory"); }
    else       { asm volatile("s_waitcnt vmcnt(4)" ::: "memory"); }
    __builtin_amdgcn_s_barrier();

    int cur = 0;
    for (int tt=0; tt<NTILE; ++tt){
        if (tt+2 < NTILE){
            int ib = cur+2; if (ib>=3) ib-=3;
            issue_tile(tt+2, ib);
        }

        {
            const int kg = tid&1;
            const int dq = (tid>>1)&127;
            const int rep = tid>>8;
            float4 rv[4];
#pragma unroll
            for (int i=0;i<4;++i){
                int r = kg*8 + rep*4 + i;
                rv[i] = *(const float4*)(&Kf[cur][r*576 + ((dq ^ (r&7))<<2)]);
            }
#pragma unroll
            for (int j=0;j<4;++j){
                uint2 o;
                o.x = pack2(((const float*)&rv[0])[j], ((const float*)&rv[1])[j]);
                o.y = pack2(((const float*)&rv[2])[j], ((const float*)&rv[3])[j]);
                *(uint2*)(Vt + vt_addr(dq*4+j, kg*8) + rep*4) = o;
            }
        }
        {
            f32x4 s0, s1;
            s0[0]=0.f; s0[1]=0.f; s0[2]=0.f; s0[3]=0.f;
            s1[0]=0.f; s1[1]=0.f; s1[2]=0.f; s1[3]=0.f;
            const float* kb = &Kf[cur][lm*576];
            const int sw = lm&7;
            __builtin_amdgcn_s_setprio(1);
#pragma unroll
            for (int ss=0;ss<3;++ss){
                if (ss < cnt){
                    int g = (cs+ss)*8 + lg*2;
                    float4 fa = *(const float4*)(kb + ((g ^ sw)<<2));
                    float4 fb = *(const float4*)(kb + (((g+1) ^ sw)<<2));
                    union{uint4 u; bf16x8 v;} cv;
                    cv.u.x = pack2(fa.x, fa.y); cv.u.y = pack2(fa.z, fa.w);
                    cv.u.z = pack2(fb.x, fb.y); cv.u.w = pack2(fb.z, fb.w);
                    s0 = __builtin_amdgcn_mfma_f32_16x16x32_bf16(qf[0][ss], cv.v, s0, 0,0,0);
                    s1 = __builtin_amdgcn_mfma_f32_16x16x32_bf16(qf[1][ss], cv.v, s1, 0,0,0);
                }
            }
            __builtin_amdgcn_s_setprio(0);
#pragma unroll
            for (int r=0;r<4;++r){
                S_s[w][(lg<<2)+r][lm]      = s0[r];
                S_s[w][16+(lg<<2)+r][lm]   = s1[r];
            }
        }
        LGKM_BARRIER();

        {
            const int kbase = k0 + tt*TK;
            float v = 0.f;
#pragma unroll
            for (int i=0;i<8;++i) v += S_s[i][myh][s5];
            v *= SM_SCALE;
            float sc = (kbase + s5 < seqlen) ? v : NEGINF;
            float tmax = sc;
            tmax = fmaxf(tmax, __shfl_xor(tmax,1));
            tmax = fmaxf(tmax, __shfl_xor(tmax,2));
            tmax = fmaxf(tmax, __shfl_xor(tmax,4));
            tmax = fmaxf(tmax, __shfl_xor(tmax,8));
            float mnew = fmaxf(m_run, tmax);
            float al = __expf(m_run - mnew);
            float pv = (sc > 0.5f*NEGINF) ? __expf(sc-mnew) : 0.f;
            P_s[myh][s5] = f2bf(pv);
            float ps = pv;
            ps += __shfl_xor(ps,1); ps += __shfl_xor(ps,2);
            ps += __shfl_xor(ps,4); ps += __shfl_xor(ps,8);
            l_run = l_run*al + ps;
            m_run = mnew;
            if (s5==0) alpha_s[myh] = al;
        }
        LGKM_BARRIER();

        {
            float al4[4];
#pragma unroll
            for (int r=0;r<4;++r) al4[r] = alpha_s[ht*16 + (lg<<2) + r];
            bf16x8 pa = *(const bf16x8*)(&P_s[ht*16+lm][lg*8]);
            __builtin_amdgcn_s_setprio(1);
#pragma unroll
            for (int nt=0;nt<8;++nt){
                f32x4 o = oacc[nt];
                o[0]*=al4[0]; o[1]*=al4[1]; o[2]*=al4[2]; o[3]*=al4[3];
                int r = dg*128 + nt*16 + lm;
                bf16x8 bv = *(const bf16x8*)(Vt + vt_addr(r, (lg&1)*8));
                oacc[nt] = __builtin_amdgcn_mfma_f32_16x16x32_bf16(pa, bv, o, 0,0,0);
            }
            __builtin_amdgcn_s_setprio(0);
        }
        if (tt+2 < NTILE){
            if (w < 4) { asm volatile("s_waitcnt vmcnt(5)" ::: "memory"); }
            else       { asm volatile("s_waitcnt vmcnt(4)" ::: "memory"); }
            __builtin_amdgcn_s_barrier();
        } else if (tt+1 < NTILE){
            asm volatile("s_waitcnt vmcnt(0)" ::: "memory");
            __builtin_amdgcn_s_barrier();
        }
        cur = cur+1; if (cur>=3) cur-=3;
    }

    const int obase = (b*NSPLIT+sp)*32;
#pragma unroll
    for (int nt=0;nt<8;++nt){
        int r = dg*128 + nt*16 + lm;
#pragma unroll
        for (int qq=0;qq<4;++qq){
            int h = ht*16 + (lg<<2) + qq;
            Opart[((size_t)(obase+h))*512 + r] = oacc[nt][qq];
        }
    }
    if (s5==0){ Mpart[obase+myh]=m_run; Lpart[obase+myh]=l_run; }
}

// ---------- av_uv via MFMA with fused split-merge + fused hi/lo pack of ao
__global__ __launch_bounds__(256) void av_uv_merge(const float* __restrict__ Opart,
        const float* __restrict__ Mpart, const float* __restrict__ Lpart,
        const float* __restrict__ wuv,
        unsigned short* __restrict__ Hi, unsigned short* __restrict__ Lo)
{
    __shared__ unsigned short Bh[4096], Bl[4096];
    __shared__ unsigned short Ah[512], Al[512];
    __shared__ float lwn[16][4];
    const int h = blockIdx.x, bg = blockIdx.y;
    const int tid = threadIdx.x;
    const int w = tid>>6, l = tid&63, lm = l&15, lg = l>>4;

    if (tid < 16){
        int b = bg*16 + tid;
        float m0 = Mpart[(b*NSPLIT+0)*32+h], m1 = Mpart[(b*NSPLIT+1)*32+h];
        float m2 = Mpart[(b*NSPLIT+2)*32+h], m3 = Mpart[(b*NSPLIT+3)*32+h];
        float M = fmaxf(fmaxf(m0,m1),fmaxf(m2,m3));
        float w0 = __expf(m0-M), w1 = __expf(m1-M), w2 = __expf(m2-M), w3 = __expf(m3-M);
        float L = w0*Lpart[(b*NSPLIT+0)*32+h] + w1*Lpart[(b*NSPLIT+1)*32+h]
                + w2*Lpart[(b*NSPLIT+2)*32+h] + w3*Lpart[(b*NSPLIT+3)*32+h];
        float inv = 1.f/L;
        lwn[tid][0]=w0*inv; lwn[tid][1]=w1*inv; lwn[tid][2]=w2*inv; lwn[tid][3]=w3*inv;
    }
    __syncthreads();

    f32x4 acc[2];
#pragma unroll
    for (int i=0;i<2;++i){ acc[i][0]=0.f; acc[i][1]=0.f; acc[i][2]=0.f; acc[i][3]=0.f; }

    for (int ck=0; ck<16; ++ck){
        const int k0 = ck*32;
        unsigned short hh[2][8], ll[2][8]; int wid0 = tid*2;
#pragma unroll
        for (int wi=0; wi<2; ++wi){
            int wid = wid0 + wi;
            int ntile = wid>>6, kg = (wid>>4)&3, nl = wid&15;
            int n = ntile*16 + nl;
            const float* wp = wuv + (size_t)h*65536 + (size_t)(k0+kg*8)*128 + n;
#pragma unroll
            for (int j=0;j<8;++j){
                float v = wp[(size_t)j*128];
                hh[wi][j] = f2bf(v);
                ll[wi][j] = f2bf(v - bf2f(hh[wi][j]));
            }
        }
        float av[2];
#pragma unroll
        for (int e=0;e<2;++e){
            int id = tid*2+e;
            int row = id>>5, k = id&31;
            int bb = bg*16 + row;
            const float* op = Opart + (((size_t)bb*NSPLIT)*32 + h)*512 + k0 + k;
            av[e] = lwn[row][0]*op[0] + lwn[row][1]*op[16384]
                  + lwn[row][2]*op[32768] + lwn[row][3]*op[49152];
        }
        __syncthreads();
#pragma unroll
        for (int wi=0; wi<2; ++wi){
            int wid = wid0 + wi;
            uint4 uh, ul;
            uh.x=(unsigned)hh[wi][0]|((unsigned)hh[wi][1]<<16); uh.y=(unsigned)hh[wi][2]|((unsigned)hh[wi][3]<<16);
            uh.z=(unsigned)hh[wi][4]|((unsigned)hh[wi][5]<<16); uh.w=(unsigned)hh[wi][6]|((unsigned)hh[wi][7]<<16);
            ul.x=(unsigned)ll[wi][0]|((unsigned)ll[wi][1]<<16); ul.y=(unsigned)ll[wi][2]|((unsigned)ll[wi][3]<<16);
            ul.z=(unsigned)ll[wi][4]|((unsigned)ll[wi][5]<<16); ul.w=(unsigned)ll[wi][6]|((unsigned)ll[wi][7]<<16);
            *(uint4*)(Bh + wid*8) = uh;
            *(uint4*)(Bl + wid*8) = ul;
        }
#pragma unroll
        for (int e=0;e<2;++e){
            int id = tid*2+e;
            int row = id>>5, k = id&31;
            unsigned short hs = f2bf(av[e]);
            unsigned short ls = f2bf(av[e] - bf2f(hs));
            int ai = ((k>>3)*16 + row)*8 + (k&7);
            Ah[ai] = hs; Al[ai] = ls;
        }
        __syncthreads();
        const int fa = (lg*16 + lm)*8;
        bf16x8 fah = *(const bf16x8*)(Ah + fa);
        bf16x8 fal = *(const bf16x8*)(Al + fa);
#pragma unroll
        for (int i=0;i<2;++i){
            int nt = w*2 + i;
            const int fb = (nt*64 + lg*16 + lm)*8;
            bf16x8 fbh = *(const bf16x8*)(Bh + fb);
            bf16x8 fbl = *(const bf16x8*)(Bl + fb);
            acc[i] = __builtin_amdgcn_mfma_f32_16x16x32_bf16(fah, fbh, acc[i], 0,0,0);
            acc[i] = __builtin_amdgcn_mfma_f32_16x16x32_bf16(fal, fbh, acc[i], 0,0,0);
            acc[i] = __builtin_amdgcn_mfma_f32_16x16x32_bf16(fah, fbl, acc[i], 0,0,0);
        }
        __syncthreads();
    }
#pragma unroll
    for (int i=0;i<2;++i){
        int nt = w*2 + i;
#pragma unroll
        for (int qq=0;qq<4;++qq){
            float val = acc[i][qq];
            int bb = bg*16 + lg*4 + qq;
            int k = h*128 + nt*16 + lm;
            unsigned short hv = f2bf(val);
            unsigned short lv = f2bf(val - bf2f(hv));
            size_t ui = (size_t)(k>>3)*512 + bb*8 + (k&7);
            Hi[ui] = hv; Lo[ui] = lv;
        }
    }
}

extern "C" void kernel_launch(void* const* d_in, const int* in_sizes, int n_in,
                              void* d_out, int out_size, void* d_ws, size_t ws_size,
                              hipStream_t stream)
{
    const float* hidden = (const float*)d_in[0];
    const float* cosb   = (const float*)d_in[1];
    const float* sinb   = (const float*)d_in[2];
    const float* kv     = (const float*)d_in[3];
    const float* w_q_a  = (const float*)d_in[4];
    const float* q_ln   = (const float*)d_in[5];
    const float* w_q_b  = (const float*)d_in[6];
    const float* w_kv_a = (const float*)d_in[7];
    const float* kv_ln  = (const float*)d_in[8];
    const float* w_uk_t = (const float*)d_in[9];
    const float* w_uv   = (const float*)d_in[10];
    const float* w_o    = (const float*)d_in[11];
    const int* slots    = (const int*)d_in[12];
    const int* seqlens  = (const int*)d_in[13];
    float* out = (float*)d_out;

    float* W = (float*)d_ws;
    float* P0     = W;                   // 4,194,304 f32 (wqa/wqb partials, attn Opart)
    float* P1     = W + 4194304;         // wkva partials (28 splits)
    float* query  = W + 6291456;
    float* latent = W + 7471104;
    float* Mp     = W + 7507968;
    float* Lp     = W + 7516160;
    unsigned short* pkq_h  = (unsigned short*)(W + 7524352);
    unsigned short* pkq_l  = (unsigned short*)(W + 7655424);
    unsigned short* pkqc_h = (unsigned short*)(W + 7786496);
    unsigned short* pkqc_l = (unsigned short*)(W + 7835648);
    unsigned short* pkao_h = (unsigned short*)(W + 7884800);
    unsigned short* pkao_l = (unsigned short*)(W + 8015872);

    // zero output for atomic accumulation (w_o GEMM)
    hipMemsetAsync(out, 0, (size_t)NB*HID*sizeof(float), stream);

    // hidden @ w_q_a (24 x 28 splits, ks=8) || hidden @ w_kv_a (9 x 28 splits, ks=8)
    hipLaunchKernelGGL(gemm_dual_raw, dim3(672+252), dim3(256), 0, stream,
                       hidden, HID, w_q_a, P0, 1536, 8, 24, 672, w_kv_a, P1, 576, 8, 9);
    hipLaunchKernelGGL(norm_dual, dim3(128), dim3(256), 0, stream,
                       P0, q_ln, pkqc_h, pkqc_l, 28, P1, kv_ln, cosb, sinb, latent, 28);
    hipLaunchKernelGGL(gemm_mfma, dim3(96,6), dim3(256), 0, stream, pkqc_h, pkqc_l, w_q_b, P0, 6144, 8);
    hipLaunchKernelGGL(finish_q, dim3(1536), dim3(256), 0, stream, P0, cosb, sinb, pkq_h, pkq_l, query, 6);
    hipLaunchKernelGGL(qlnope_mfma, dim3(32,4), dim3(256), 0, stream, pkq_h, pkq_l, w_uk_t, query);
    hipLaunchKernelGGL(attn_mfma, dim3(NSPLIT,64), dim3(512), 0, stream,
                       query, kv, latent, slots, seqlens, P0, Mp, Lp);
    hipLaunchKernelGGL(av_uv_merge, dim3(32,4), dim3(256), 0, stream, P0, Mp, Lp, w_uv, pkao_h, pkao_l);
    hipLaunchKernelGGL(gemm_atomic, dim3(112,8), dim3(256), 0, stream, pkao_h, pkao_l, w_o, out, 7168, 16);
}

// Round 15
// 328.392 us; speedup vs baseline: 1.0622x; 1.0622x over previous
//
#include <hip/hip_runtime.h>
#include <stdint.h>

#define NB 64
#define NH 32
#define KCTX 4096
#define HID 7168
#define QLORA 1536
#define KVL 512
#define DTOT 576
#define NSPLIT 4
#define KSPAN 1024
#define NTILE 64           // KSPAN/16
#define TK 16
#define SM_SCALE 0.07216878364870323f  // 1/sqrt(192)
#define NEGINF (-3.0e38f)

typedef __attribute__((ext_vector_type(4))) float f32x4;
typedef __attribute__((ext_vector_type(8))) __bf16 bf16x8;

#define LGKM_BARRIER() do{ asm volatile("s_waitcnt lgkmcnt(0)" ::: "memory"); __builtin_amdgcn_s_barrier(); } while(0)

static __device__ __forceinline__ void glds16(const void* g, void* s){
    __builtin_amdgcn_global_load_lds((const __attribute__((address_space(1))) void*)g,
                                     (__attribute__((address_space(3))) void*)s, 16, 0, 0);
}

static __device__ __forceinline__ unsigned short f2bf(float f){
    union{__bf16 h; unsigned short s;} x; x.h = (__bf16)f; return x.s;
}
static __device__ __forceinline__ float bf2f(unsigned short h){
    union{unsigned i;float f;}x; x.i=((unsigned)h)<<16; return x.f;
}
static __device__ __forceinline__ unsigned pack2(float a, float b){
    union{__bf16 h[2]; unsigned u;} x; x.h[0]=(__bf16)a; x.h[1]=(__bf16)b; return x.u;
}

// ================= GEMM cores =================
// Epilogue mode: 0 = write partials P[s][m][n]; 1 = unsafeAtomicAdd into Out[m][n]
template<int OUT_MODE>
static __device__ __forceinline__ void gemm_core_packed(
        const unsigned short* __restrict__ Ahi, const unsigned short* __restrict__ Alo,
        const float* __restrict__ Wm, float* __restrict__ P, int N, int ksteps,
        int bx, int by,
        unsigned short* Ah, unsigned short* Al, unsigned short* Bh, unsigned short* Bl)
{
    const int tid = threadIdx.x;
    const int w = tid>>6, l = tid&63, lm = l&15, lg = l>>4;
    const int n0 = bx*64;
    const int s  = by;
    const int mn = tid&63, ks = tid>>6;
    const int widx = ((mn>>4)*64 + ks*16 + (mn&15));

    f32x4 acc[4];
#pragma unroll
    for (int i=0;i<4;++i){ acc[i][0]=0.f; acc[i][1]=0.f; acc[i][2]=0.f; acc[i][3]=0.f; }

    uint4 ah4, al4; float wv[8];
    auto load_raw = [&](int t){
        const int k0 = (s*ksteps + t)*32;
        size_t gidx = (size_t)((k0>>3) + ks)*64 + mn;
        ah4 = *(const uint4*)(Ahi + gidx*8);
        al4 = *(const uint4*)(Alo + gidx*8);
        const float* wp = Wm + (size_t)(k0 + ks*8)*N + n0 + mn;
#pragma unroll
        for (int j=0;j<8;++j) wv[j] = wp[(size_t)j*N];
    };
    auto cvt_write = [&](int buf){
        unsigned short h8[8], l8[8];
#pragma unroll
        for (int j=0;j<8;++j){
            h8[j] = f2bf(wv[j]);
            l8[j] = f2bf(wv[j] - bf2f(h8[j]));
        }
        uint4 bh4, bl4;
        bh4.x=(unsigned)h8[0]|((unsigned)h8[1]<<16); bh4.y=(unsigned)h8[2]|((unsigned)h8[3]<<16);
        bh4.z=(unsigned)h8[4]|((unsigned)h8[5]<<16); bh4.w=(unsigned)h8[6]|((unsigned)h8[7]<<16);
        bl4.x=(unsigned)l8[0]|((unsigned)l8[1]<<16); bl4.y=(unsigned)l8[2]|((unsigned)l8[3]<<16);
        bl4.z=(unsigned)l8[4]|((unsigned)l8[5]<<16); bl4.w=(unsigned)l8[6]|((unsigned)l8[7]<<16);
        *(uint4*)(Ah + buf*2048 + widx*8) = ah4;
        *(uint4*)(Al + buf*2048 + widx*8) = al4;
        *(uint4*)(Bh + buf*2048 + widx*8) = bh4;
        *(uint4*)(Bl + buf*2048 + widx*8) = bl4;
    };

    load_raw(0);
    for (int t=0; t<ksteps; ++t){
        const int buf = t&1;
        cvt_write(buf);
        __syncthreads();
        if (t+1 < ksteps) load_raw(t+1);
        const int fa = buf*2048 + (w*64 + lg*16 + lm)*8;
        bf16x8 fah = *(const bf16x8*)(Ah + fa);
        bf16x8 fal = *(const bf16x8*)(Al + fa);
#pragma unroll
        for (int nt=0;nt<4;++nt){
            const int fb = buf*2048 + (nt*64 + lg*16 + lm)*8;
            bf16x8 fbh = *(const bf16x8*)(Bh + fb);
            bf16x8 fbl = *(const bf16x8*)(Bl + fb);
            acc[nt] = __builtin_amdgcn_mfma_f32_16x16x32_bf16(fah, fbh, acc[nt], 0,0,0);
            acc[nt] = __builtin_amdgcn_mfma_f32_16x16x32_bf16(fal, fbh, acc[nt], 0,0,0);
            acc[nt] = __builtin_amdgcn_mfma_f32_16x16x32_bf16(fah, fbl, acc[nt], 0,0,0);
        }
        __syncthreads();
    }
#pragma unroll
    for (int nt=0;nt<4;++nt){
        int n = n0 + nt*16 + lm;
#pragma unroll
        for (int r=0;r<4;++r){
            int m = w*16 + lg*4 + r;
            if (OUT_MODE == 0) P[((size_t)s*64 + m)*N + n] = acc[nt][r];
            else               unsafeAtomicAdd(&P[(size_t)m*N + n], acc[nt][r]);
        }
    }
}

// raw fp32 A (A[64][KA] row-major), converted in-register
static __device__ __forceinline__ void gemm_core_raw(
        const float* __restrict__ Araw, int KA,
        const float* __restrict__ Wm, float* __restrict__ P, int N, int ksteps,
        int bx, int by,
        unsigned short* Ah, unsigned short* Al, unsigned short* Bh, unsigned short* Bl)
{
    const int tid = threadIdx.x;
    const int w = tid>>6, l = tid&63, lm = l&15, lg = l>>4;
    const int n0 = bx*64;
    const int s  = by;
    const int mn = tid&63, ks = tid>>6;
    const int widx = ((mn>>4)*64 + ks*16 + (mn&15));

    f32x4 acc[4];
#pragma unroll
    for (int i=0;i<4;++i){ acc[i][0]=0.f; acc[i][1]=0.f; acc[i][2]=0.f; acc[i][3]=0.f; }

    float av[8], wv[8];
    auto load_raw = [&](int t){
        const int k0 = (s*ksteps + t)*32;
        const float* ap = Araw + (size_t)mn*KA + k0 + ks*8;
        *(float4*)(av)   = *(const float4*)(ap);
        *(float4*)(av+4) = *(const float4*)(ap+4);
        const float* wp = Wm + (size_t)(k0 + ks*8)*N + n0 + mn;
#pragma unroll
        for (int j=0;j<8;++j) wv[j] = wp[(size_t)j*N];
    };
    auto cvt_write = [&](int buf){
        unsigned short ha[8], la[8], hb[8], lb[8];
#pragma unroll
        for (int j=0;j<8;++j){
            ha[j] = f2bf(av[j]); la[j] = f2bf(av[j] - bf2f(ha[j]));
            hb[j] = f2bf(wv[j]); lb[j] = f2bf(wv[j] - bf2f(hb[j]));
        }
        uint4 ah4, al4, bh4, bl4;
        ah4.x=(unsigned)ha[0]|((unsigned)ha[1]<<16); ah4.y=(unsigned)ha[2]|((unsigned)ha[3]<<16);
        ah4.z=(unsigned)ha[4]|((unsigned)ha[5]<<16); ah4.w=(unsigned)ha[6]|((unsigned)ha[7]<<16);
        al4.x=(unsigned)la[0]|((unsigned)la[1]<<16); al4.y=(unsigned)la[2]|((unsigned)la[3]<<16);
        al4.z=(unsigned)la[4]|((unsigned)la[5]<<16); al4.w=(unsigned)la[6]|((unsigned)la[7]<<16);
        bh4.x=(unsigned)hb[0]|((unsigned)hb[1]<<16); bh4.y=(unsigned)hb[2]|((unsigned)hb[3]<<16);
        bh4.z=(unsigned)hb[4]|((unsigned)hb[5]<<16); bh4.w=(unsigned)hb[6]|((unsigned)hb[7]<<16);
        bl4.x=(unsigned)lb[0]|((unsigned)lb[1]<<16); bl4.y=(unsigned)lb[2]|((unsigned)lb[3]<<16);
        bl4.z=(unsigned)lb[4]|((unsigned)lb[5]<<16); bl4.w=(unsigned)lb[6]|((unsigned)lb[7]<<16);
        *(uint4*)(Ah + buf*2048 + widx*8) = ah4;
        *(uint4*)(Al + buf*2048 + widx*8) = al4;
        *(uint4*)(Bh + buf*2048 + widx*8) = bh4;
        *(uint4*)(Bl + buf*2048 + widx*8) = bl4;
    };

    load_raw(0);
    for (int t=0; t<ksteps; ++t){
        const int buf = t&1;
        cvt_write(buf);
        __syncthreads();
        if (t+1 < ksteps) load_raw(t+1);
        const int fa = buf*2048 + (w*64 + lg*16 + lm)*8;
        bf16x8 fah = *(const bf16x8*)(Ah + fa);
        bf16x8 fal = *(const bf16x8*)(Al + fa);
#pragma unroll
        for (int nt=0;nt<4;++nt){
            const int fb = buf*2048 + (nt*64 + lg*16 + lm)*8;
            bf16x8 fbh = *(const bf16x8*)(Bh + fb);
            bf16x8 fbl = *(const bf16x8*)(Bl + fb);
            acc[nt] = __builtin_amdgcn_mfma_f32_16x16x32_bf16(fah, fbh, acc[nt], 0,0,0);
            acc[nt] = __builtin_amdgcn_mfma_f32_16x16x32_bf16(fal, fbh, acc[nt], 0,0,0);
            acc[nt] = __builtin_amdgcn_mfma_f32_16x16x32_bf16(fah, fbl, acc[nt], 0,0,0);
        }
        __syncthreads();
    }
#pragma unroll
    for (int nt=0;nt<4;++nt){
        int n = n0 + nt*16 + lm;
#pragma unroll
        for (int r=0;r<4;++r){
            int m = w*16 + lg*4 + r;
            P[((size_t)s*64 + m)*N + n] = acc[nt][r];
        }
    }
}

__global__ __launch_bounds__(256) void gemm_mfma(
        const unsigned short* __restrict__ Ahi, const unsigned short* __restrict__ Alo,
        const float* __restrict__ Wm, float* __restrict__ P, int N, int ksteps)
{
    __shared__ unsigned short Ah[2*2048], Al[2*2048], Bh[2*2048], Bl[2*2048];
    gemm_core_packed<0>(Ahi, Alo, Wm, P, N, ksteps, blockIdx.x, blockIdx.y, Ah, Al, Bh, Bl);
}

__global__ __launch_bounds__(256) void gemm_atomic(
        const unsigned short* __restrict__ Ahi, const unsigned short* __restrict__ Alo,
        const float* __restrict__ Wm, float* __restrict__ Out, int N, int ksteps)
{
    __shared__ unsigned short Ah[2*2048], Al[2*2048], Bh[2*2048], Bl[2*2048];
    gemm_core_packed<1>(Ahi, Alo, Wm, Out, N, ksteps, blockIdx.x, blockIdx.y, Ah, Al, Bh, Bl);
}

// two independent raw-A GEMMs in one launch (hidden @ w_q_a || hidden @ w_kv_a)
__global__ __launch_bounds__(256) void gemm_dual_raw(
        const float* __restrict__ Araw, int KA,
        const float* __restrict__ W0, float* __restrict__ P0, int N0, int ks0, int nbx0, int nblk0,
        const float* __restrict__ W1, float* __restrict__ P1, int N1, int ks1, int nbx1)
{
    __shared__ unsigned short Ah[2*2048], Al[2*2048], Bh[2*2048], Bl[2*2048];
    int bid = blockIdx.x;
    if (bid < nblk0){
        gemm_core_raw(Araw, KA, W0, P0, N0, ks0, bid%nbx0, bid/nbx0, Ah, Al, Bh, Bl);
    } else {
        bid -= nblk0;
        gemm_core_raw(Araw, KA, W1, P1, N1, ks1, bid%nbx1, bid/nbx1, Ah, Al, Bh, Bl);
    }
}

// ================= norms =================
static __device__ __forceinline__ void rms_core(const float* __restrict__ P,
        const float* __restrict__ w, unsigned short* __restrict__ Hi,
        unsigned short* __restrict__ Lo, int S, int b, float* red)
{
    const int t = threadIdx.x;
    float v[6]; float ss = 0.f;
#pragma unroll
    for (int j=0;j<6;++j){
        int n = j*256 + t;
        float s = 0.f;
        for (int sp=0; sp<S; ++sp) s += P[((size_t)sp*64+b)*1536 + n];
        v[j] = s; ss += s*s;
    }
#pragma unroll
    for (int off=32; off>=1; off>>=1) ss += __shfl_xor(ss, off, 64);
    if ((t&63)==0) red[t>>6] = ss;
    __syncthreads();
    float tot = red[0]+red[1]+red[2]+red[3];
    float rs = rsqrtf(tot/1536.f + 1e-6f);
#pragma unroll
    for (int j=0;j<6;++j){
        int n = j*256+t;
        float val = v[j]*rs*w[n];
        unsigned short hs = f2bf(val);
        unsigned short ls = f2bf(val - bf2f(hs));
        size_t ui = (size_t)(n>>3)*512 + b*8 + (n&7);
        Hi[ui] = hs; Lo[ui] = ls;
    }
}

static __device__ __forceinline__ void kvrope_core(const float* __restrict__ P,
        const float* __restrict__ w, const float* __restrict__ cosb, const float* __restrict__ sinb,
        float* __restrict__ latent, int S, int b, float* vals, float* red)
{
    const int t = threadIdx.x;
    float ss = 0.f;
    for (int j=0;j<3;++j){
        int n = j*256+t;
        if (n < 576){
            float s=0.f;
            for (int sp=0;sp<S;++sp) s += P[((size_t)sp*64+b)*576 + n];
            vals[n]=s;
            if (n<512) ss += s*s;
        }
    }
#pragma unroll
    for (int off=32; off>=1; off>>=1) ss += __shfl_xor(ss, off, 64);
    if ((t&63)==0) red[t>>6]=ss;
    __syncthreads();
    float tot = red[0]+red[1]+red[2]+red[3];
    float rs = rsqrtf(tot/512.f + 1e-6f);
    for (int j=0;j<3;++j){
        int n = j*256+t;
        if (n<576){
            float o;
            if (n < 512) o = vals[n]*rs*w[n];
            else if (n < 544){ int i=n-512; o = vals[512+2*i]*cosb[b*32+i] - vals[513+2*i]*sinb[b*32+i]; }
            else            { int i=n-544; o = vals[513+2*i]*cosb[b*32+i] + vals[512+2*i]*sinb[b*32+i]; }
            latent[(size_t)b*576 + n] = o;
        }
    }
}

__global__ __launch_bounds__(256) void norm_dual(
        const float* __restrict__ Pq, const float* __restrict__ qw,
        unsigned short* __restrict__ Hi, unsigned short* __restrict__ Lo, int Sq,
        const float* __restrict__ Pkv, const float* __restrict__ kvw,
        const float* __restrict__ cosb, const float* __restrict__ sinb,
        float* __restrict__ latent, int Skv)
{
    __shared__ float vals[576];
    __shared__ float red[4];
    if (blockIdx.x < 64) rms_core(Pq, qw, Hi, Lo, Sq, blockIdx.x, red);
    else                 kvrope_core(Pkv, kvw, cosb, sinb, latent, Skv, blockIdx.x-64, vals, red);
}

// ---------- finish q: reduce partials; nope part -> packed hi/lo A; rope -> query[512..]
__global__ __launch_bounds__(256) void finish_q(const float* __restrict__ P,
        const float* __restrict__ cosb, const float* __restrict__ sinb,
        unsigned short* __restrict__ qh, unsigned short* __restrict__ ql,
        float* __restrict__ query, int S)
{
    int i = blockIdx.x*256 + threadIdx.x;
    int b = i / 6144, n = i - b*6144;
    float s = 0.f;
    for (int sp=0; sp<S; ++sp) s += P[((size_t)sp*64+b)*6144 + n];
    int h = n/192, nl = n - h*192;
    if (nl < 128){
        unsigned short hs = f2bf(s);
        unsigned short ls = f2bf(s - bf2f(hs));
        size_t ui = (size_t)h*8192 + (size_t)(nl>>3)*512 + b*8 + (nl&7);
        qh[ui]=hs; ql[ui]=ls;
    } else {
        int i2 = (nl-128)>>1;
        float other = __shfl_xor(s, 1);
        float c = cosb[b*32+i2], sn = sinb[b*32+i2];
        float* o = query + ((size_t)b*32+h)*576;
        if ((nl&1)==0) o[512+i2] = s*c - other*sn;
        else           o[544+i2] = s*c + other*sn;
    }
}

// ---------- ql_nope via MFMA, packed A
__global__ __launch_bounds__(256) void qlnope_mfma(const unsigned short* __restrict__ qh,
        const unsigned short* __restrict__ ql,
        const float* __restrict__ wukt, float* __restrict__ query)
{
    __shared__ unsigned short Bh[4096], Bl[4096];
    const int h = blockIdx.x, r0 = blockIdx.y*128;
    const int tid = threadIdx.x;
    const int w = tid>>6, l = tid&63, lm = l&15, lg = l>>4;
    f32x4 acc[8];
#pragma unroll
    for (int i=0;i<8;++i){ acc[i][0]=0.f; acc[i][1]=0.f; acc[i][2]=0.f; acc[i][3]=0.f; }

    for (int ck=0; ck<4; ++ck){
        const int k0 = ck*32;
        unsigned short hh[2][8], ll[2][8]; int wid0 = tid*2;
#pragma unroll
        for (int wi=0; wi<2; ++wi){
            int wid = wid0 + wi;
            int ntile = wid>>6, kg = (wid>>4)&3, nl = wid&15;
            int n = r0 + ntile*16 + nl;
            const float* wp = wukt + (size_t)h*65536 + (size_t)(k0+kg*8)*512 + n;
#pragma unroll
            for (int j=0;j<8;++j){
                float v = wp[(size_t)j*512];
                hh[wi][j] = f2bf(v);
                ll[wi][j] = f2bf(v - bf2f(hh[wi][j]));
            }
        }
        __syncthreads();
#pragma unroll
        for (int wi=0; wi<2; ++wi){
            int wid = wid0 + wi;
            uint4 uh, ul;
            uh.x=(unsigned)hh[wi][0]|((unsigned)hh[wi][1]<<16); uh.y=(unsigned)hh[wi][2]|((unsigned)hh[wi][3]<<16);
            uh.z=(unsigned)hh[wi][4]|((unsigned)hh[wi][5]<<16); uh.w=(unsigned)hh[wi][6]|((unsigned)hh[wi][7]<<16);
            ul.x=(unsigned)ll[wi][0]|((unsigned)ll[wi][1]<<16); ul.y=(unsigned)ll[wi][2]|((unsigned)ll[wi][3]<<16);
            ul.z=(unsigned)ll[wi][4]|((unsigned)ll[wi][5]<<16); ul.w=(unsigned)ll[wi][6]|((unsigned)ll[wi][7]<<16);
            *(uint4*)(Bh + wid*8) = uh;
            *(uint4*)(Bl + wid*8) = ul;
        }
        __syncthreads();
        size_t ai = (size_t)h*8192 + (size_t)(ck*4+lg)*512 + (size_t)(w*16+lm)*8;
        union{uint4 u; bf16x8 v;} fh, fl;
        fh.u = *(const uint4*)(qh + ai);
        fl.u = *(const uint4*)(ql + ai);
#pragma unroll
        for (int nt=0;nt<8;++nt){
            const int fb = (nt*64 + lg*16 + lm)*8;
            bf16x8 fbh = *(const bf16x8*)(Bh + fb);
            bf16x8 fbl = *(const bf16x8*)(Bl + fb);
            acc[nt] = __builtin_amdgcn_mfma_f32_16x16x32_bf16(fh.v, fbh, acc[nt], 0,0,0);
            acc[nt] = __builtin_amdgcn_mfma_f32_16x16x32_bf16(fl.v, fbh, acc[nt], 0,0,0);
            acc[nt] = __builtin_amdgcn_mfma_f32_16x16x32_bf16(fh.v, fbl, acc[nt], 0,0,0);
        }
        __syncthreads();
    }
#pragma unroll
    for (int nt=0;nt<8;++nt){
        int r = r0 + nt*16 + lm;
#pragma unroll
        for (int qq=0;qq<4;++qq){
            int bb = w*16 + lg*4 + qq;
            query[((size_t)bb*32 + h)*576 + r] = acc[nt][qq];
        }
    }
}

// Vt flat layout: addr_u16(d,key) = (d>>2)*64 + ((d&3)^((d>>3)&3))*16 + key
static __device__ __forceinline__ int vt_addr(int d, int key){
    return (d>>2)*64 + (((d&3)^((d>>3)&3))<<4) + key;
}

// ---------- flash decode attention v8: 512 thr, triple-buffer DMA, counted vmcnt,
// QK = 8 d-group waves x dual-ht MFMA (K converted once per chunk)
__global__ __launch_bounds__(512,1) void attn_mfma(const float* __restrict__ query,
        const float* __restrict__ kv, const float* __restrict__ latent,
        const int* __restrict__ slots, const int* __restrict__ seq_lens,
        float* __restrict__ Opart, float* __restrict__ Mpart, float* __restrict__ Lpart)
{
    __shared__ float Kf[3][16*576];
    __shared__ unsigned short Vt[8192];
    __shared__ float S_s[8][32][16];
    __shared__ unsigned short P_s[32][40];
    __shared__ float alpha_s[32];

    const int b = blockIdx.y, sp = blockIdx.x;
    const int tid = threadIdx.x;
    const int w = tid>>6, l = tid&63;
    const int lm = l&15, lg = l>>4;
    const int ht = w&1;
    const int dg = w>>1;
    const int cs = 2*w + (w>=1?1:0) + (w>=5?1:0);
    const int cnt = ((w&3)==0)?3:2;
    const int seqlen = seq_lens[b];
    const int slot = slots[b];
    const int k0 = sp*KSPAN;
    const int myh = tid>>4, s5 = tid&15;

    P_s[tid>>4][16 + (tid&15)] = 0;

    bf16x8 qf[2][3];
#pragma unroll
    for (int h2=0; h2<2; ++h2){
        const float* qrow = query + ((size_t)b*32 + h2*16 + lm)*576;
#pragma unroll
        for (int ss=0;ss<3;++ss){
            union{uint4 u; bf16x8 v;} cv;
            if (ss < cnt){
                int d0 = (cs+ss)*32 + lg*8;
                float4 a = *(const float4*)(qrow + d0);
                float4 c = *(const float4*)(qrow + d0 + 4);
                cv.u.x=pack2(a.x,a.y); cv.u.y=pack2(a.z,a.w);
                cv.u.z=pack2(c.x,c.y); cv.u.w=pack2(c.z,c.w);
            } else {
                cv.u.x=0; cv.u.y=0; cv.u.z=0; cv.u.w=0;
            }
            qf[h2][ss]=cv.v;
        }
    }

    auto issue_tile = [&](int tt, int buf){
        const int gkb = k0 + tt*TK;
#pragma unroll
        for (int i=0;i<5;++i){
            int s = i*8 + w;
            if (s < 36){
                int B = s*1024 + l*16;
                int r = B / 2304;
                int gs = (B - r*2304) >> 4;
                int g  = gs ^ (r&7);
                int gk = gkb + r; if (gk > KCTX-1) gk = KCTX-1;
                const float* src = (gk==slot) ? (latent + (size_t)b*576 + g*4)
                                              : (kv + ((size_t)b*KCTX + gk)*576 + g*4);
                glds16(src, ((char*)&Kf[buf][0]) + B);
            }
        }
    };

    f32x4 oacc[8];
#pragma unroll
    for (int i=0;i<8;++i){ oacc[i][0]=0.f; oacc[i][1]=0.f; oacc[i][2]=0.f; oacc[i][3]=0.f; }
    float m_run = NEGINF, l_run = 0.f;

    issue_tile(0, 0);
    issue_tile(1, 1);
    if (w < 4) { asm volatile("s_waitcnt vmcnt(5)" ::: "memory"); }
    else       { asm volatile("s_waitcnt vmcnt(4)" ::: "memory"); }
    __builtin_amdgcn_s_barrier();

    int cur = 0;
    for (int tt=0; tt<NTILE; ++tt){
        if (tt+2 < NTILE){
            int ib = cur+2; if (ib>=3) ib-=3;
            issue_tile(tt+2, ib);
        }

        {
            const int kg = tid&1;
            const int dq = (tid>>1)&127;
            const int rep = tid>>8;
            float4 rv[4];
#pragma unroll
            for (int i=0;i<4;++i){
                int r = kg*8 + rep*4 + i;
                rv[i] = *(const float4*)(&Kf[cur][r*576 + ((dq ^ (r&7))<<2)]);
            }
#pragma unroll
            for (int j=0;j<4;++j){
                uint2 o;
                o.x = pack2(((const float*)&rv[0])[j], ((const float*)&rv[1])[j]);
                o.y = pack2(((const float*)&rv[2])[j], ((const float*)&rv[3])[j]);
                *(uint2*)(Vt + vt_addr(dq*4+j, kg*8) + rep*4) = o;
            }
        }
        {
            f32x4 s0, s1;
            s0[0]=0.f; s0[1]=0.f; s0[2]=0.f; s0[3]=0.f;
            s1[0]=0.f; s1[1]=0.f; s1[2]=0.f; s1[3]=0.f;
            const float* kb = &Kf[cur][lm*576];
            const int sw = lm&7;
            __builtin_amdgcn_s_setprio(1);
#pragma unroll
            for (int ss=0;ss<3;++ss){
                if (ss < cnt){
                    int g = (cs+ss)*8 + lg*2;
                    float4 fa = *(const float4*)(kb + ((g ^ sw)<<2));
                    float4 fb = *(const float4*)(kb + (((g+1) ^ sw)<<2));
                    union{uint4 u; bf16x8 v;} cv;
                    cv.u.x = pack2(fa.x, fa.y); cv.u.y = pack2(fa.z, fa.w);
                    cv.u.z = pack2(fb.x, fb.y); cv.u.w = pack2(fb.z, fb.w);
                    s0 = __builtin_amdgcn_mfma_f32_16x16x32_bf16(qf[0][ss], cv.v, s0, 0,0,0);
                    s1 = __builtin_amdgcn_mfma_f32_16x16x32_bf16(qf[1][ss], cv.v, s1, 0,0,0);
                }
            }
            __builtin_amdgcn_s_setprio(0);
#pragma unroll
            for (int r=0;r<4;++r){
                S_s[w][(lg<<2)+r][lm]      = s0[r];
                S_s[w][16+(lg<<2)+r][lm]   = s1[r];
            }
        }
        LGKM_BARRIER();

        {
            const int kbase = k0 + tt*TK;
            float v = 0.f;
#pragma unroll
            for (int i=0;i<8;++i) v += S_s[i][myh][s5];
            v *= SM_SCALE;
            float sc = (kbase + s5 < seqlen) ? v : NEGINF;
            float tmax = sc;
            tmax = fmaxf(tmax, __shfl_xor(tmax,1));
            tmax = fmaxf(tmax, __shfl_xor(tmax,2));
            tmax = fmaxf(tmax, __shfl_xor(tmax,4));
            tmax = fmaxf(tmax, __shfl_xor(tmax,8));
            float mnew = fmaxf(m_run, tmax);
            float al = __expf(m_run - mnew);
            float pv = (sc > 0.5f*NEGINF) ? __expf(sc-mnew) : 0.f;
            P_s[myh][s5] = f2bf(pv);
            float ps = pv;
            ps += __shfl_xor(ps,1); ps += __shfl_xor(ps,2);
            ps += __shfl_xor(ps,4); ps += __shfl_xor(ps,8);
            l_run = l_run*al + ps;
            m_run = mnew;
            if (s5==0) alpha_s[myh] = al;
        }
        LGKM_BARRIER();

        {
            float al4[4];
#pragma unroll
            for (int r=0;r<4;++r) al4[r] = alpha_s[ht*16 + (lg<<2) + r];
            bf16x8 pa = *(const bf16x8*)(&P_s[ht*16+lm][lg*8]);
            __builtin_amdgcn_s_setprio(1);
#pragma unroll
            for (int nt=0;nt<8;++nt){
                f32x4 o = oacc[nt];
                o[0]*=al4[0]; o[1]*=al4[1]; o[2]*=al4[2]; o[3]*=al4[3];
                int r = dg*128 + nt*16 + lm;
                bf16x8 bv = *(const bf16x8*)(Vt + vt_addr(r, (lg&1)*8));
                oacc[nt] = __builtin_amdgcn_mfma_f32_16x16x32_bf16(pa, bv, o, 0,0,0);
            }
            __builtin_amdgcn_s_setprio(0);
        }
        if (tt+2 < NTILE){
            if (w < 4) { asm volatile("s_waitcnt vmcnt(5)" ::: "memory"); }
            else       { asm volatile("s_waitcnt vmcnt(4)" ::: "memory"); }
            __builtin_amdgcn_s_barrier();
        } else if (tt+1 < NTILE){
            asm volatile("s_waitcnt vmcnt(0)" ::: "memory");
            __builtin_amdgcn_s_barrier();
        }
        cur = cur+1; if (cur>=3) cur-=3;
    }

    const int obase = (b*NSPLIT+sp)*32;
#pragma unroll
    for (int nt=0;nt<8;++nt){
        int r = dg*128 + nt*16 + lm;
#pragma unroll
        for (int qq=0;qq<4;++qq){
            int h = ht*16 + (lg<<2) + qq;
            Opart[((size_t)(obase+h))*512 + r] = oacc[nt][qq];
        }
    }
    if (s5==0){ Mpart[obase+myh]=m_run; Lpart[obase+myh]=l_run; }
}

// ---------- av_uv via MFMA with fused split-merge + fused hi/lo pack of ao
__global__ __launch_bounds__(256) void av_uv_merge(const float* __restrict__ Opart,
        const float* __restrict__ Mpart, const float* __restrict__ Lpart,
        const float* __restrict__ wuv,
        unsigned short* __restrict__ Hi, unsigned short* __restrict__ Lo)
{
    __shared__ unsigned short Bh[4096], Bl[4096];
    __shared__ unsigned short Ah[512], Al[512];
    __shared__ float lwn[16][4];
    const int h = blockIdx.x, bg = blockIdx.y;
    const int tid = threadIdx.x;
    const int w = tid>>6, l = tid&63, lm = l&15, lg = l>>4;

    if (tid < 16){
        int b = bg*16 + tid;
        float m0 = Mpart[(b*NSPLIT+0)*32+h], m1 = Mpart[(b*NSPLIT+1)*32+h];
        float m2 = Mpart[(b*NSPLIT+2)*32+h], m3 = Mpart[(b*NSPLIT+3)*32+h];
        float M = fmaxf(fmaxf(m0,m1),fmaxf(m2,m3));
        float w0 = __expf(m0-M), w1 = __expf(m1-M), w2 = __expf(m2-M), w3 = __expf(m3-M);
        float L = w0*Lpart[(b*NSPLIT+0)*32+h] + w1*Lpart[(b*NSPLIT+1)*32+h]
                + w2*Lpart[(b*NSPLIT+2)*32+h] + w3*Lpart[(b*NSPLIT+3)*32+h];
        float inv = 1.f/L;
        lwn[tid][0]=w0*inv; lwn[tid][1]=w1*inv; lwn[tid][2]=w2*inv; lwn[tid][3]=w3*inv;
    }
    __syncthreads();

    f32x4 acc[2];
#pragma unroll
    for (int i=0;i<2;++i){ acc[i][0]=0.f; acc[i][1]=0.f; acc[i][2]=0.f; acc[i][3]=0.f; }

    for (int ck=0; ck<16; ++ck){
        const int k0 = ck*32;
        unsigned short hh[2][8], ll[2][8]; int wid0 = tid*2;
#pragma unroll
        for (int wi=0; wi<2; ++wi){
            int wid = wid0 + wi;
            int ntile = wid>>6, kg = (wid>>4)&3, nl = wid&15;
            int n = ntile*16 + nl;
            const float* wp = wuv + (size_t)h*65536 + (size_t)(k0+kg*8)*128 + n;
#pragma unroll
            for (int j=0;j<8;++j){
                float v = wp[(size_t)j*128];
                hh[wi][j] = f2bf(v);
                ll[wi][j] = f2bf(v - bf2f(hh[wi][j]));
            }
        }
        float av[2];
#pragma unroll
        for (int e=0;e<2;++e){
            int id = tid*2+e;
            int row = id>>5, k = id&31;
            int bb = bg*16 + row;
            const float* op = Opart + (((size_t)bb*NSPLIT)*32 + h)*512 + k0 + k;
            av[e] = lwn[row][0]*op[0] + lwn[row][1]*op[16384]
                  + lwn[row][2]*op[32768] + lwn[row][3]*op[49152];
        }
        __syncthreads();
#pragma unroll
        for (int wi=0; wi<2; ++wi){
            int wid = wid0 + wi;
            uint4 uh, ul;
            uh.x=(unsigned)hh[wi][0]|((unsigned)hh[wi][1]<<16); uh.y=(unsigned)hh[wi][2]|((unsigned)hh[wi][3]<<16);
            uh.z=(unsigned)hh[wi][4]|((unsigned)hh[wi][5]<<16); uh.w=(unsigned)hh[wi][6]|((unsigned)hh[wi][7]<<16);
            ul.x=(unsigned)ll[wi][0]|((unsigned)ll[wi][1]<<16); ul.y=(unsigned)ll[wi][2]|((unsigned)ll[wi][3]<<16);
            ul.z=(unsigned)ll[wi][4]|((unsigned)ll[wi][5]<<16); ul.w=(unsigned)ll[wi][6]|((unsigned)ll[wi][7]<<16);
            *(uint4*)(Bh + wid*8) = uh;
            *(uint4*)(Bl + wid*8) = ul;
        }
#pragma unroll
        for (int e=0;e<2;++e){
            int id = tid*2+e;
            int row = id>>5, k = id&31;
            unsigned short hs = f2bf(av[e]);
            unsigned short ls = f2bf(av[e] - bf2f(hs));
            int ai = ((k>>3)*16 + row)*8 + (k&7);
            Ah[ai] = hs; Al[ai] = ls;
        }
        __syncthreads();
        const int fa = (lg*16 + lm)*8;
        bf16x8 fah = *(const bf16x8*)(Ah + fa);
        bf16x8 fal = *(const bf16x8*)(Al + fa);
#pragma unroll
        for (int i=0;i<2;++i){
            int nt = w*2 + i;
            const int fb = (nt*64 + lg*16 + lm)*8;
            bf16x8 fbh = *(const bf16x8*)(Bh + fb);
            bf16x8 fbl = *(const bf16x8*)(Bl + fb);
            acc[i] = __builtin_amdgcn_mfma_f32_16x16x32_bf16(fah, fbh, acc[i], 0,0,0);
            acc[i] = __builtin_amdgcn_mfma_f32_16x16x32_bf16(fal, fbh, acc[i], 0,0,0);
            acc[i] = __builtin_amdgcn_mfma_f32_16x16x32_bf16(fah, fbl, acc[i], 0,0,0);
        }
        __syncthreads();
    }
#pragma unroll
    for (int i=0;i<2;++i){
        int nt = w*2 + i;
#pragma unroll
        for (int qq=0;qq<4;++qq){
            float val = acc[i][qq];
            int bb = bg*16 + lg*4 + qq;
            int k = h*128 + nt*16 + lm;
            unsigned short hv = f2bf(val);
            unsigned short lv = f2bf(val - bf2f(hv));
            size_t ui = (size_t)(k>>3)*512 + bb*8 + (k&7);
            Hi[ui] = hv; Lo[ui] = lv;
        }
    }
}

extern "C" void kernel_launch(void* const* d_in, const int* in_sizes, int n_in,
                              void* d_out, int out_size, void* d_ws, size_t ws_size,
                              hipStream_t stream)
{
    const float* hidden = (const float*)d_in[0];
    const float* cosb   = (const float*)d_in[1];
    const float* sinb   = (const float*)d_in[2];
    const float* kv     = (const float*)d_in[3];
    const float* w_q_a  = (const float*)d_in[4];
    const float* q_ln   = (const float*)d_in[5];
    const float* w_q_b  = (const float*)d_in[6];
    const float* w_kv_a = (const float*)d_in[7];
    const float* kv_ln  = (const float*)d_in[8];
    const float* w_uk_t = (const float*)d_in[9];
    const float* w_uv   = (const float*)d_in[10];
    const float* w_o    = (const float*)d_in[11];
    const int* slots    = (const int*)d_in[12];
    const int* seqlens  = (const int*)d_in[13];
    float* out = (float*)d_out;

    float* W = (float*)d_ws;
    float* P0     = W;                   // 4,194,304 f32 (wqa/wqb partials, attn Opart)
    float* P1     = W + 4194304;         // 2,097,152 (wkva partials, 28 splits = 1,032,192)
    float* query  = W + 6291456;         // 1,179,648
    float* latent = W + 7471104;         // 36,864
    float* Mp     = W + 7507968;         // 8,192
    float* Lp     = W + 7516160;         // 8,192
    unsigned short* pkq_h  = (unsigned short*)(W + 7524352);   // 131,072 f32 each
    unsigned short* pkq_l  = (unsigned short*)(W + 7655424);
    unsigned short* pkqc_h = (unsigned short*)(W + 7786496);   // 49,152 f32 each
    unsigned short* pkqc_l = (unsigned short*)(W + 7835648);
    unsigned short* pkao_h = (unsigned short*)(W + 7884800);   // 131,072 f32 each
    unsigned short* pkao_l = (unsigned short*)(W + 8015872);   // end 8,146,944

    // zero output for atomic accumulation (w_o GEMM)
    hipMemsetAsync(out, 0, (size_t)NB*HID*sizeof(float), stream);

    // hidden @ w_q_a (24 x 28 splits, ks=8) || hidden @ w_kv_a (9 x 28 splits, ks=8)
    hipLaunchKernelGGL(gemm_dual_raw, dim3(672+252), dim3(256), 0, stream,
                       hidden, HID, w_q_a, P0, 1536, 8, 24, 672, w_kv_a, P1, 576, 8, 9);
    hipLaunchKernelGGL(norm_dual, dim3(128), dim3(256), 0, stream,
                       P0, q_ln, pkqc_h, pkqc_l, 28, P1, kv_ln, cosb, sinb, latent, 28);
    hipLaunchKernelGGL(gemm_mfma, dim3(96,6), dim3(256), 0, stream, pkqc_h, pkqc_l, w_q_b, P0, 6144, 8);
    hipLaunchKernelGGL(finish_q, dim3(1536), dim3(256), 0, stream, P0, cosb, sinb, pkq_h, pkq_l, query, 6);
    hipLaunchKernelGGL(qlnope_mfma, dim3(32,4), dim3(256), 0, stream, pkq_h, pkq_l, w_uk_t, query);
    hipLaunchKernelGGL(attn_mfma, dim3(NSPLIT,64), dim3(512), 0, stream,
                       query, kv, latent, slots, seqlens, P0, Mp, Lp);
    hipLaunchKernelGGL(av_uv_merge, dim3(32,4), dim3(256), 0, stream, P0, Mp, Lp, w_uv, pkao_h, pkao_l);
    hipLaunchKernelGGL(gemm_atomic, dim3(112,8), dim3(256), 0, stream, pkao_h, pkao_l, w_o, out, 7168, 16);
}

// Round 16
// 327.618 us; speedup vs baseline: 1.0647x; 1.0024x over previous
//
#include <hip/hip_runtime.h>
#include <stdint.h>

#define NB 64
#define NH 32
#define KCTX 4096
#define HID 7168
#define QLORA 1536
#define KVL 512
#define DTOT 576
#define NSPLIT 4
#define KSPAN 1024
#define NTILE 64           // KSPAN/16
#define TK 16
#define SM_SCALE 0.07216878364870323f  // 1/sqrt(192)
#define NEGINF (-3.0e38f)

typedef __attribute__((ext_vector_type(4))) float f32x4;
typedef __attribute__((ext_vector_type(8))) __bf16 bf16x8;

#define LGKM_BARRIER() do{ asm volatile("s_waitcnt lgkmcnt(0)" ::: "memory"); __builtin_amdgcn_s_barrier(); } while(0)

static __device__ __forceinline__ void glds16(const void* g, void* s){
    __builtin_amdgcn_global_load_lds((const __attribute__((address_space(1))) void*)g,
                                     (__attribute__((address_space(3))) void*)s, 16, 0, 0);
}

static __device__ __forceinline__ unsigned short f2bf(float f){
    union{__bf16 h; unsigned short s;} x; x.h = (__bf16)f; return x.s;
}
static __device__ __forceinline__ float bf2f(unsigned short h){
    union{unsigned i;float f;}x; x.i=((unsigned)h)<<16; return x.f;
}
static __device__ __forceinline__ unsigned pack2(float a, float b){
    union{__bf16 h[2]; unsigned u;} x; x.h[0]=(__bf16)a; x.h[1]=(__bf16)b; return x.u;
}

// ================= GEMM cores =================
// Epilogue mode: 0 = write partials P[s][m][n]; 1 = unsafeAtomicAdd into Out[m][n]
template<int OUT_MODE>
static __device__ __forceinline__ void gemm_core_packed(
        const unsigned short* __restrict__ Ahi, const unsigned short* __restrict__ Alo,
        const float* __restrict__ Wm, float* __restrict__ P, int N, int ksteps,
        int bx, int by,
        unsigned short* Ah, unsigned short* Al, unsigned short* Bh, unsigned short* Bl)
{
    const int tid = threadIdx.x;
    const int w = tid>>6, l = tid&63, lm = l&15, lg = l>>4;
    const int n0 = bx*64;
    const int s  = by;
    const int mn = tid&63, ks = tid>>6;
    const int widx = ((mn>>4)*64 + ks*16 + (mn&15));

    f32x4 acc[4];
#pragma unroll
    for (int i=0;i<4;++i){ acc[i][0]=0.f; acc[i][1]=0.f; acc[i][2]=0.f; acc[i][3]=0.f; }

    uint4 ah4, al4; float wv[8];
    auto load_raw = [&](int t){
        const int k0 = (s*ksteps + t)*32;
        size_t gidx = (size_t)((k0>>3) + ks)*64 + mn;
        ah4 = *(const uint4*)(Ahi + gidx*8);
        al4 = *(const uint4*)(Alo + gidx*8);
        const float* wp = Wm + (size_t)(k0 + ks*8)*N + n0 + mn;
#pragma unroll
        for (int j=0;j<8;++j) wv[j] = wp[(size_t)j*N];
    };
    auto cvt_write = [&](int buf){
        unsigned short h8[8], l8[8];
#pragma unroll
        for (int j=0;j<8;++j){
            h8[j] = f2bf(wv[j]);
            l8[j] = f2bf(wv[j] - bf2f(h8[j]));
        }
        uint4 bh4, bl4;
        bh4.x=(unsigned)h8[0]|((unsigned)h8[1]<<16); bh4.y=(unsigned)h8[2]|((unsigned)h8[3]<<16);
        bh4.z=(unsigned)h8[4]|((unsigned)h8[5]<<16); bh4.w=(unsigned)h8[6]|((unsigned)h8[7]<<16);
        bl4.x=(unsigned)l8[0]|((unsigned)l8[1]<<16); bl4.y=(unsigned)l8[2]|((unsigned)l8[3]<<16);
        bl4.z=(unsigned)l8[4]|((unsigned)l8[5]<<16); bl4.w=(unsigned)l8[6]|((unsigned)l8[7]<<16);
        *(uint4*)(Ah + buf*2048 + widx*8) = ah4;
        *(uint4*)(Al + buf*2048 + widx*8) = al4;
        *(uint4*)(Bh + buf*2048 + widx*8) = bh4;
        *(uint4*)(Bl + buf*2048 + widx*8) = bl4;
    };

    load_raw(0);
    for (int t=0; t<ksteps; ++t){
        const int buf = t&1;
        cvt_write(buf);
        __syncthreads();
        if (t+1 < ksteps) load_raw(t+1);
        const int fa = buf*2048 + (w*64 + lg*16 + lm)*8;
        bf16x8 fah = *(const bf16x8*)(Ah + fa);
        bf16x8 fal = *(const bf16x8*)(Al + fa);
#pragma unroll
        for (int nt=0;nt<4;++nt){
            const int fb = buf*2048 + (nt*64 + lg*16 + lm)*8;
            bf16x8 fbh = *(const bf16x8*)(Bh + fb);
            bf16x8 fbl = *(const bf16x8*)(Bl + fb);
            acc[nt] = __builtin_amdgcn_mfma_f32_16x16x32_bf16(fah, fbh, acc[nt], 0,0,0);
            acc[nt] = __builtin_amdgcn_mfma_f32_16x16x32_bf16(fal, fbh, acc[nt], 0,0,0);
            acc[nt] = __builtin_amdgcn_mfma_f32_16x16x32_bf16(fah, fbl, acc[nt], 0,0,0);
        }
        __syncthreads();
    }
#pragma unroll
    for (int nt=0;nt<4;++nt){
        int n = n0 + nt*16 + lm;
#pragma unroll
        for (int r=0;r<4;++r){
            int m = w*16 + lg*4 + r;
            if (OUT_MODE == 0) P[((size_t)s*64 + m)*N + n] = acc[nt][r];
            else               unsafeAtomicAdd(&P[(size_t)m*N + n], acc[nt][r]);
        }
    }
}

// raw fp32 A (A[64][KA] row-major), converted in-register
static __device__ __forceinline__ void gemm_core_raw(
        const float* __restrict__ Araw, int KA,
        const float* __restrict__ Wm, float* __restrict__ P, int N, int ksteps,
        int bx, int by,
        unsigned short* Ah, unsigned short* Al, unsigned short* Bh, unsigned short* Bl)
{
    const int tid = threadIdx.x;
    const int w = tid>>6, l = tid&63, lm = l&15, lg = l>>4;
    const int n0 = bx*64;
    const int s  = by;
    const int mn = tid&63, ks = tid>>6;
    const int widx = ((mn>>4)*64 + ks*16 + (mn&15));

    f32x4 acc[4];
#pragma unroll
    for (int i=0;i<4;++i){ acc[i][0]=0.f; acc[i][1]=0.f; acc[i][2]=0.f; acc[i][3]=0.f; }

    float av[8], wv[8];
    auto load_raw = [&](int t){
        const int k0 = (s*ksteps + t)*32;
        const float* ap = Araw + (size_t)mn*KA + k0 + ks*8;
        *(float4*)(av)   = *(const float4*)(ap);
        *(float4*)(av+4) = *(const float4*)(ap+4);
        const float* wp = Wm + (size_t)(k0 + ks*8)*N + n0 + mn;
#pragma unroll
        for (int j=0;j<8;++j) wv[j] = wp[(size_t)j*N];
    };
    auto cvt_write = [&](int buf){
        unsigned short ha[8], la[8], hb[8], lb[8];
#pragma unroll
        for (int j=0;j<8;++j){
            ha[j] = f2bf(av[j]); la[j] = f2bf(av[j] - bf2f(ha[j]));
            hb[j] = f2bf(wv[j]); lb[j] = f2bf(wv[j] - bf2f(hb[j]));
        }
        uint4 ah4, al4, bh4, bl4;
        ah4.x=(unsigned)ha[0]|((unsigned)ha[1]<<16); ah4.y=(unsigned)ha[2]|((unsigned)ha[3]<<16);
        ah4.z=(unsigned)ha[4]|((unsigned)ha[5]<<16); ah4.w=(unsigned)ha[6]|((unsigned)ha[7]<<16);
        al4.x=(unsigned)la[0]|((unsigned)la[1]<<16); al4.y=(unsigned)la[2]|((unsigned)la[3]<<16);
        al4.z=(unsigned)la[4]|((unsigned)la[5]<<16); al4.w=(unsigned)la[6]|((unsigned)la[7]<<16);
        bh4.x=(unsigned)hb[0]|((unsigned)hb[1]<<16); bh4.y=(unsigned)hb[2]|((unsigned)hb[3]<<16);
        bh4.z=(unsigned)hb[4]|((unsigned)hb[5]<<16); bh4.w=(unsigned)hb[6]|((unsigned)hb[7]<<16);
        bl4.x=(unsigned)lb[0]|((unsigned)lb[1]<<16); bl4.y=(unsigned)lb[2]|((unsigned)lb[3]<<16);
        bl4.z=(unsigned)lb[4]|((unsigned)lb[5]<<16); bl4.w=(unsigned)lb[6]|((unsigned)lb[7]<<16);
        *(uint4*)(Ah + buf*2048 + widx*8) = ah4;
        *(uint4*)(Al + buf*2048 + widx*8) = al4;
        *(uint4*)(Bh + buf*2048 + widx*8) = bh4;
        *(uint4*)(Bl + buf*2048 + widx*8) = bl4;
    };

    load_raw(0);
    for (int t=0; t<ksteps; ++t){
        const int buf = t&1;
        cvt_write(buf);
        __syncthreads();
        if (t+1 < ksteps) load_raw(t+1);
        const int fa = buf*2048 + (w*64 + lg*16 + lm)*8;
        bf16x8 fah = *(const bf16x8*)(Ah + fa);
        bf16x8 fal = *(const bf16x8*)(Al + fa);
#pragma unroll
        for (int nt=0;nt<4;++nt){
            const int fb = buf*2048 + (nt*64 + lg*16 + lm)*8;
            bf16x8 fbh = *(const bf16x8*)(Bh + fb);
            bf16x8 fbl = *(const bf16x8*)(Bl + fb);
            acc[nt] = __builtin_amdgcn_mfma_f32_16x16x32_bf16(fah, fbh, acc[nt], 0,0,0);
            acc[nt] = __builtin_amdgcn_mfma_f32_16x16x32_bf16(fal, fbh, acc[nt], 0,0,0);
            acc[nt] = __builtin_amdgcn_mfma_f32_16x16x32_bf16(fah, fbl, acc[nt], 0,0,0);
        }
        __syncthreads();
    }
#pragma unroll
    for (int nt=0;nt<4;++nt){
        int n = n0 + nt*16 + lm;
#pragma unroll
        for (int r=0;r<4;++r){
            int m = w*16 + lg*4 + r;
            P[((size_t)s*64 + m)*N + n] = acc[nt][r];
        }
    }
}

__global__ __launch_bounds__(256) void gemm_mfma(
        const unsigned short* __restrict__ Ahi, const unsigned short* __restrict__ Alo,
        const float* __restrict__ Wm, float* __restrict__ P, int N, int ksteps)
{
    __shared__ unsigned short Ah[2*2048], Al[2*2048], Bh[2*2048], Bl[2*2048];
    gemm_core_packed<0>(Ahi, Alo, Wm, P, N, ksteps, blockIdx.x, blockIdx.y, Ah, Al, Bh, Bl);
}

__global__ __launch_bounds__(256) void gemm_atomic(
        const unsigned short* __restrict__ Ahi, const unsigned short* __restrict__ Alo,
        const float* __restrict__ Wm, float* __restrict__ Out, int N, int ksteps)
{
    __shared__ unsigned short Ah[2*2048], Al[2*2048], Bh[2*2048], Bl[2*2048];
    gemm_core_packed<1>(Ahi, Alo, Wm, Out, N, ksteps, blockIdx.x, blockIdx.y, Ah, Al, Bh, Bl);
}

// two independent raw-A GEMMs in one launch (hidden @ w_q_a || hidden @ w_kv_a)
__global__ __launch_bounds__(256) void gemm_dual_raw(
        const float* __restrict__ Araw, int KA,
        const float* __restrict__ W0, float* __restrict__ P0, int N0, int ks0, int nbx0, int nblk0,
        const float* __restrict__ W1, float* __restrict__ P1, int N1, int ks1, int nbx1)
{
    __shared__ unsigned short Ah[2*2048], Al[2*2048], Bh[2*2048], Bl[2*2048];
    int bid = blockIdx.x;
    if (bid < nblk0){
        gemm_core_raw(Araw, KA, W0, P0, N0, ks0, bid%nbx0, bid/nbx0, Ah, Al, Bh, Bl);
    } else {
        bid -= nblk0;
        gemm_core_raw(Araw, KA, W1, P1, N1, ks1, bid%nbx1, bid/nbx1, Ah, Al, Bh, Bl);
    }
}

// ================= norms =================
static __device__ __forceinline__ void rms_core(const float* __restrict__ P,
        const float* __restrict__ w, unsigned short* __restrict__ Hi,
        unsigned short* __restrict__ Lo, int S, int b, float* red)
{
    const int t = threadIdx.x;
    float v[6]; float ss = 0.f;
#pragma unroll
    for (int j=0;j<6;++j){
        int n = j*256 + t;
        float s = 0.f;
        for (int sp=0; sp<S; ++sp) s += P[((size_t)sp*64+b)*1536 + n];
        v[j] = s; ss += s*s;
    }
#pragma unroll
    for (int off=32; off>=1; off>>=1) ss += __shfl_xor(ss, off, 64);
    if ((t&63)==0) red[t>>6] = ss;
    __syncthreads();
    float tot = red[0]+red[1]+red[2]+red[3];
    float rs = rsqrtf(tot/1536.f + 1e-6f);
#pragma unroll
    for (int j=0;j<6;++j){
        int n = j*256+t;
        float val = v[j]*rs*w[n];
        unsigned short hs = f2bf(val);
        unsigned short ls = f2bf(val - bf2f(hs));
        size_t ui = (size_t)(n>>3)*512 + b*8 + (n&7);
        Hi[ui] = hs; Lo[ui] = ls;
    }
}

static __device__ __forceinline__ void kvrope_core(const float* __restrict__ P,
        const float* __restrict__ w, const float* __restrict__ cosb, const float* __restrict__ sinb,
        float* __restrict__ latent, int S, int b, float* vals, float* red)
{
    const int t = threadIdx.x;
    float ss = 0.f;
    for (int j=0;j<3;++j){
        int n = j*256+t;
        if (n < 576){
            float s=0.f;
            for (int sp=0;sp<S;++sp) s += P[((size_t)sp*64+b)*576 + n];
            vals[n]=s;
            if (n<512) ss += s*s;
        }
    }
#pragma unroll
    for (int off=32; off>=1; off>>=1) ss += __shfl_xor(ss, off, 64);
    if ((t&63)==0) red[t>>6]=ss;
    __syncthreads();
    float tot = red[0]+red[1]+red[2]+red[3];
    float rs = rsqrtf(tot/512.f + 1e-6f);
    for (int j=0;j<3;++j){
        int n = j*256+t;
        if (n<576){
            float o;
            if (n < 512) o = vals[n]*rs*w[n];
            else if (n < 544){ int i=n-512; o = vals[512+2*i]*cosb[b*32+i] - vals[513+2*i]*sinb[b*32+i]; }
            else            { int i=n-544; o = vals[513+2*i]*cosb[b*32+i] + vals[512+2*i]*sinb[b*32+i]; }
            latent[(size_t)b*576 + n] = o;
        }
    }
}

__global__ __launch_bounds__(256) void norm_dual(
        const float* __restrict__ Pq, const float* __restrict__ qw,
        unsigned short* __restrict__ Hi, unsigned short* __restrict__ Lo, int Sq,
        const float* __restrict__ Pkv, const float* __restrict__ kvw,
        const float* __restrict__ cosb, const float* __restrict__ sinb,
        float* __restrict__ latent, int Skv)
{
    __shared__ float vals[576];
    __shared__ float red[4];
    if (blockIdx.x < 64) rms_core(Pq, qw, Hi, Lo, Sq, blockIdx.x, red);
    else                 kvrope_core(Pkv, kvw, cosb, sinb, latent, Skv, blockIdx.x-64, vals, red);
}

// ---------- finish q: reduce partials; nope part -> packed hi/lo A; rope -> query[512..]
__global__ __launch_bounds__(256) void finish_q(const float* __restrict__ P,
        const float* __restrict__ cosb, const float* __restrict__ sinb,
        unsigned short* __restrict__ qh, unsigned short* __restrict__ ql,
        float* __restrict__ query, int S)
{
    int i = blockIdx.x*256 + threadIdx.x;
    int b = i / 6144, n = i - b*6144;
    float s = 0.f;
    for (int sp=0; sp<S; ++sp) s += P[((size_t)sp*64+b)*6144 + n];
    int h = n/192, nl = n - h*192;
    if (nl < 128){
        unsigned short hs = f2bf(s);
        unsigned short ls = f2bf(s - bf2f(hs));
        size_t ui = (size_t)h*8192 + (size_t)(nl>>3)*512 + b*8 + (nl&7);
        qh[ui]=hs; ql[ui]=ls;
    } else {
        int i2 = (nl-128)>>1;
        float other = __shfl_xor(s, 1);
        float c = cosb[b*32+i2], sn = sinb[b*32+i2];
        float* o = query + ((size_t)b*32+h)*576;
        if ((nl&1)==0) o[512+i2] = s*c - other*sn;
        else           o[544+i2] = s*c + other*sn;
    }
}

// ---------- ql_nope via MFMA, packed A
__global__ __launch_bounds__(256) void qlnope_mfma(const unsigned short* __restrict__ qh,
        const unsigned short* __restrict__ ql,
        const float* __restrict__ wukt, float* __restrict__ query)
{
    __shared__ unsigned short Bh[4096], Bl[4096];
    const int h = blockIdx.x, r0 = blockIdx.y*128;
    const int tid = threadIdx.x;
    const int w = tid>>6, l = tid&63, lm = l&15, lg = l>>4;
    f32x4 acc[8];
#pragma unroll
    for (int i=0;i<8;++i){ acc[i][0]=0.f; acc[i][1]=0.f; acc[i][2]=0.f; acc[i][3]=0.f; }

    for (int ck=0; ck<4; ++ck){
        const int k0 = ck*32;
        unsigned short hh[2][8], ll[2][8]; int wid0 = tid*2;
#pragma unroll
        for (int wi=0; wi<2; ++wi){
            int wid = wid0 + wi;
            int ntile = wid>>6, kg = (wid>>4)&3, nl = wid&15;
            int n = r0 + ntile*16 + nl;
            const float* wp = wukt + (size_t)h*65536 + (size_t)(k0+kg*8)*512 + n;
#pragma unroll
            for (int j=0;j<8;++j){
                float v = wp[(size_t)j*512];
                hh[wi][j] = f2bf(v);
                ll[wi][j] = f2bf(v - bf2f(hh[wi][j]));
            }
        }
        __syncthreads();
#pragma unroll
        for (int wi=0; wi<2; ++wi){
            int wid = wid0 + wi;
            uint4 uh, ul;
            uh.x=(unsigned)hh[wi][0]|((unsigned)hh[wi][1]<<16); uh.y=(unsigned)hh[wi][2]|((unsigned)hh[wi][3]<<16);
            uh.z=(unsigned)hh[wi][4]|((unsigned)hh[wi][5]<<16); uh.w=(unsigned)hh[wi][6]|((unsigned)hh[wi][7]<<16);
            ul.x=(unsigned)ll[wi][0]|((unsigned)ll[wi][1]<<16); ul.y=(unsigned)ll[wi][2]|((unsigned)ll[wi][3]<<16);
            ul.z=(unsigned)ll[wi][4]|((unsigned)ll[wi][5]<<16); ul.w=(unsigned)ll[wi][6]|((unsigned)ll[wi][7]<<16);
            *(uint4*)(Bh + wid*8) = uh;
            *(uint4*)(Bl + wid*8) = ul;
        }
        __syncthreads();
        size_t ai = (size_t)h*8192 + (size_t)(ck*4+lg)*512 + (size_t)(w*16+lm)*8;
        union{uint4 u; bf16x8 v;} fh, fl;
        fh.u = *(const uint4*)(qh + ai);
        fl.u = *(const uint4*)(ql + ai);
#pragma unroll
        for (int nt=0;nt<8;++nt){
            const int fb = (nt*64 + lg*16 + lm)*8;
            bf16x8 fbh = *(const bf16x8*)(Bh + fb);
            bf16x8 fbl = *(const bf16x8*)(Bl + fb);
            acc[nt] = __builtin_amdgcn_mfma_f32_16x16x32_bf16(fh.v, fbh, acc[nt], 0,0,0);
            acc[nt] = __builtin_amdgcn_mfma_f32_16x16x32_bf16(fl.v, fbh, acc[nt], 0,0,0);
            acc[nt] = __builtin_amdgcn_mfma_f32_16x16x32_bf16(fh.v, fbl, acc[nt], 0,0,0);
        }
        __syncthreads();
    }
#pragma unroll
    for (int nt=0;nt<8;++nt){
        int r = r0 + nt*16 + lm;
#pragma unroll
        for (int qq=0;qq<4;++qq){
            int bb = w*16 + lg*4 + qq;
            query[((size_t)bb*32 + h)*576 + r] = acc[nt][qq];
        }
    }
}

// Vt flat layout: addr_u16(d,key) = (d>>2)*64 + ((d&3)^((d>>3)&3))*16 + key
static __device__ __forceinline__ int vt_addr(int d, int key){
    return (d>>2)*64 + (((d&3)^((d>>3)&3))<<4) + key;
}

// ---------- flash decode attention v8: 512 thr, triple-buffer DMA, counted vmcnt,
// QK = 8 d-group waves x dual-ht MFMA (K converted once per chunk)
__global__ __launch_bounds__(512,1) void attn_mfma(const float* __restrict__ query,
        const float* __restrict__ kv, const float* __restrict__ latent,
        const int* __restrict__ slots, const int* __restrict__ seq_lens,
        float* __restrict__ Opart, float* __restrict__ Mpart, float* __restrict__ Lpart)
{
    __shared__ float Kf[3][16*576];
    __shared__ unsigned short Vt[8192];
    __shared__ float S_s[8][32][16];
    __shared__ unsigned short P_s[32][40];
    __shared__ float alpha_s[32];

    const int b = blockIdx.y, sp = blockIdx.x;
    const int tid = threadIdx.x;
    const int w = tid>>6, l = tid&63;
    const int lm = l&15, lg = l>>4;
    const int ht = w&1;
    const int dg = w>>1;
    const int cs = 2*w + (w>=1?1:0) + (w>=5?1:0);
    const int cnt = ((w&3)==0)?3:2;
    const int seqlen = seq_lens[b];
    const int slot = slots[b];
    const int k0 = sp*KSPAN;
    const int myh = tid>>4, s5 = tid&15;

    P_s[tid>>4][16 + (tid&15)] = 0;

    bf16x8 qf[2][3];
#pragma unroll
    for (int h2=0; h2<2; ++h2){
        const float* qrow = query + ((size_t)b*32 + h2*16 + lm)*576;
#pragma unroll
        for (int ss=0;ss<3;++ss){
            union{uint4 u; bf16x8 v;} cv;
            if (ss < cnt){
                int d0 = (cs+ss)*32 + lg*8;
                float4 a = *(const float4*)(qrow + d0);
                float4 c = *(const float4*)(qrow + d0 + 4);
                cv.u.x=pack2(a.x,a.y); cv.u.y=pack2(a.z,a.w);
                cv.u.z=pack2(c.x,c.y); cv.u.w=pack2(c.z,c.w);
            } else {
                cv.u.x=0; cv.u.y=0; cv.u.z=0; cv.u.w=0;
            }
            qf[h2][ss]=cv.v;
        }
    }

    auto issue_tile = [&](int tt, int buf){
        const int gkb = k0 + tt*TK;
#pragma unroll
        for (int i=0;i<5;++i){
            int s = i*8 + w;
            if (s < 36){
                int B = s*1024 + l*16;
                int r = B / 2304;
                int gs = (B - r*2304) >> 4;
                int g  = gs ^ (r&7);
                int gk = gkb + r; if (gk > KCTX-1) gk = KCTX-1;
                const float* src = (gk==slot) ? (latent + (size_t)b*576 + g*4)
                                              : (kv + ((size_t)b*KCTX + gk)*576 + g*4);
                glds16(src, ((char*)&Kf[buf][0]) + B);
            }
        }
    };

    f32x4 oacc[8];
#pragma unroll
    for (int i=0;i<8;++i){ oacc[i][0]=0.f; oacc[i][1]=0.f; oacc[i][2]=0.f; oacc[i][3]=0.f; }
    float m_run = NEGINF, l_run = 0.f;

    issue_tile(0, 0);
    issue_tile(1, 1);
    if (w < 4) { asm volatile("s_waitcnt vmcnt(5)" ::: "memory"); }
    else       { asm volatile("s_waitcnt vmcnt(4)" ::: "memory"); }
    __builtin_amdgcn_s_barrier();

    int cur = 0;
    for (int tt=0; tt<NTILE; ++tt){
        if (tt+2 < NTILE){
            int ib = cur+2; if (ib>=3) ib-=3;
            issue_tile(tt+2, ib);
        }

        {
            const int kg = tid&1;
            const int dq = (tid>>1)&127;
            const int rep = tid>>8;
            float4 rv[4];
#pragma unroll
            for (int i=0;i<4;++i){
                int r = kg*8 + rep*4 + i;
                rv[i] = *(const float4*)(&Kf[cur][r*576 + ((dq ^ (r&7))<<2)]);
            }
#pragma unroll
            for (int j=0;j<4;++j){
                uint2 o;
                o.x = pack2(((const float*)&rv[0])[j], ((const float*)&rv[1])[j]);
                o.y = pack2(((const float*)&rv[2])[j], ((const float*)&rv[3])[j]);
                *(uint2*)(Vt + vt_addr(dq*4+j, kg*8) + rep*4) = o;
            }
        }
        {
            f32x4 s0, s1;
            s0[0]=0.f; s0[1]=0.f; s0[2]=0.f; s0[3]=0.f;
            s1[0]=0.f; s1[1]=0.f; s1[2]=0.f; s1[3]=0.f;
            const float* kb = &Kf[cur][lm*576];
            const int sw = lm&7;
            __builtin_amdgcn_s_setprio(1);
#pragma unroll
            for (int ss=0;ss<3;++ss){
                if (ss < cnt){
                    int g = (cs+ss)*8 + lg*2;
                    float4 fa = *(const float4*)(kb + ((g ^ sw)<<2));
                    float4 fb = *(const float4*)(kb + (((g+1) ^ sw)<<2));
                    union{uint4 u; bf16x8 v;} cv;
                    cv.u.x = pack2(fa.x, fa.y); cv.u.y = pack2(fa.z, fa.w);
                    cv.u.z = pack2(fb.x, fb.y); cv.u.w = pack2(fb.z, fb.w);
                    s0 = __builtin_amdgcn_mfma_f32_16x16x32_bf16(qf[0][ss], cv.v, s0, 0,0,0);
                    s1 = __builtin_amdgcn_mfma_f32_16x16x32_bf16(qf[1][ss], cv.v, s1, 0,0,0);
                }
            }
            __builtin_amdgcn_s_setprio(0);
#pragma unroll
            for (int r=0;r<4;++r){
                S_s[w][(lg<<2)+r][lm]      = s0[r];
                S_s[w][16+(lg<<2)+r][lm]   = s1[r];
            }
        }
        LGKM_BARRIER();

        {
            const int kbase = k0 + tt*TK;
            float v = 0.f;
#pragma unroll
            for (int i=0;i<8;++i) v += S_s[i][myh][s5];
            v *= SM_SCALE;
            float sc = (kbase + s5 < seqlen) ? v : NEGINF;
            float tmax = sc;
            tmax = fmaxf(tmax, __shfl_xor(tmax,1));
            tmax = fmaxf(tmax, __shfl_xor(tmax,2));
            tmax = fmaxf(tmax, __shfl_xor(tmax,4));
            tmax = fmaxf(tmax, __shfl_xor(tmax,8));
            float mnew = fmaxf(m_run, tmax);
            float al = __expf(m_run - mnew);
            float pv = (sc > 0.5f*NEGINF) ? __expf(sc-mnew) : 0.f;
            P_s[myh][s5] = f2bf(pv);
            float ps = pv;
            ps += __shfl_xor(ps,1); ps += __shfl_xor(ps,2);
            ps += __shfl_xor(ps,4); ps += __shfl_xor(ps,8);
            l_run = l_run*al + ps;
            m_run = mnew;
            if (s5==0) alpha_s[myh] = al;
        }
        LGKM_BARRIER();

        {
            float al4[4];
#pragma unroll
            for (int r=0;r<4;++r) al4[r] = alpha_s[ht*16 + (lg<<2) + r];
            bf16x8 pa = *(const bf16x8*)(&P_s[ht*16+lm][lg*8]);
            __builtin_amdgcn_s_setprio(1);
#pragma unroll
            for (int nt=0;nt<8;++nt){
                f32x4 o = oacc[nt];
                o[0]*=al4[0]; o[1]*=al4[1]; o[2]*=al4[2]; o[3]*=al4[3];
                int r = dg*128 + nt*16 + lm;
                bf16x8 bv = *(const bf16x8*)(Vt + vt_addr(r, (lg&1)*8));
                oacc[nt] = __builtin_amdgcn_mfma_f32_16x16x32_bf16(pa, bv, o, 0,0,0);
            }
            __builtin_amdgcn_s_setprio(0);
        }
        if (tt+2 < NTILE){
            if (w < 4) { asm volatile("s_waitcnt vmcnt(5)" ::: "memory"); }
            else       { asm volatile("s_waitcnt vmcnt(4)" ::: "memory"); }
            __builtin_amdgcn_s_barrier();
        } else if (tt+1 < NTILE){
            asm volatile("s_waitcnt vmcnt(0)" ::: "memory");
            __builtin_amdgcn_s_barrier();
        }
        cur = cur+1; if (cur>=3) cur-=3;
    }

    const int obase = (b*NSPLIT+sp)*32;
#pragma unroll
    for (int nt=0;nt<8;++nt){
        int r = dg*128 + nt*16 + lm;
#pragma unroll
        for (int qq=0;qq<4;++qq){
            int h = ht*16 + (lg<<2) + qq;
            Opart[((size_t)(obase+h))*512 + r] = oacc[nt][qq];
        }
    }
    if (s5==0){ Mpart[obase+myh]=m_run; Lpart[obase+myh]=l_run; }
}

// ---------- av_uv via MFMA with fused split-merge + fused hi/lo pack of ao
__global__ __launch_bounds__(256) void av_uv_merge(const float* __restrict__ Opart,
        const float* __restrict__ Mpart, const float* __restrict__ Lpart,
        const float* __restrict__ wuv,
        unsigned short* __restrict__ Hi, unsigned short* __restrict__ Lo)
{
    __shared__ unsigned short Bh[4096], Bl[4096];
    __shared__ unsigned short Ah[512], Al[512];
    __shared__ float lwn[16][4];
    const int h = blockIdx.x, bg = blockIdx.y;
    const int tid = threadIdx.x;
    const int w = tid>>6, l = tid&63, lm = l&15, lg = l>>4;

    if (tid < 16){
        int b = bg*16 + tid;
        float m0 = Mpart[(b*NSPLIT+0)*32+h], m1 = Mpart[(b*NSPLIT+1)*32+h];
        float m2 = Mpart[(b*NSPLIT+2)*32+h], m3 = Mpart[(b*NSPLIT+3)*32+h];
        float M = fmaxf(fmaxf(m0,m1),fmaxf(m2,m3));
        float w0 = __expf(m0-M), w1 = __expf(m1-M), w2 = __expf(m2-M), w3 = __expf(m3-M);
        float L = w0*Lpart[(b*NSPLIT+0)*32+h] + w1*Lpart[(b*NSPLIT+1)*32+h]
                + w2*Lpart[(b*NSPLIT+2)*32+h] + w3*Lpart[(b*NSPLIT+3)*32+h];
        float inv = 1.f/L;
        lwn[tid][0]=w0*inv; lwn[tid][1]=w1*inv; lwn[tid][2]=w2*inv; lwn[tid][3]=w3*inv;
    }
    __syncthreads();

    f32x4 acc[2];
#pragma unroll
    for (int i=0;i<2;++i){ acc[i][0]=0.f; acc[i][1]=0.f; acc[i][2]=0.f; acc[i][3]=0.f; }

    for (int ck=0; ck<16; ++ck){
        const int k0 = ck*32;
        unsigned short hh[2][8], ll[2][8]; int wid0 = tid*2;
#pragma unroll
        for (int wi=0; wi<2; ++wi){
            int wid = wid0 + wi;
            int ntile = wid>>6, kg = (wid>>4)&3, nl = wid&15;
            int n = ntile*16 + nl;
            const float* wp = wuv + (size_t)h*65536 + (size_t)(k0+kg*8)*128 + n;
#pragma unroll
            for (int j=0;j<8;++j){
                float v = wp[(size_t)j*128];
                hh[wi][j] = f2bf(v);
                ll[wi][j] = f2bf(v - bf2f(hh[wi][j]));
            }
        }
        float av[2];
#pragma unroll
        for (int e=0;e<2;++e){
            int id = tid*2+e;
            int row = id>>5, k = id&31;
            int bb = bg*16 + row;
            const float* op = Opart + (((size_t)bb*NSPLIT)*32 + h)*512 + k0 + k;
            av[e] = lwn[row][0]*op[0] + lwn[row][1]*op[16384]
                  + lwn[row][2]*op[32768] + lwn[row][3]*op[49152];
        }
        __syncthreads();
#pragma unroll
        for (int wi=0; wi<2; ++wi){
            int wid = wid0 + wi;
            uint4 uh, ul;
            uh.x=(unsigned)hh[wi][0]|((unsigned)hh[wi][1]<<16); uh.y=(unsigned)hh[wi][2]|((unsigned)hh[wi][3]<<16);
            uh.z=(unsigned)hh[wi][4]|((unsigned)hh[wi][5]<<16); uh.w=(unsigned)hh[wi][6]|((unsigned)hh[wi][7]<<16);
            ul.x=(unsigned)ll[wi][0]|((unsigned)ll[wi][1]<<16); ul.y=(unsigned)ll[wi][2]|((unsigned)ll[wi][3]<<16);
            ul.z=(unsigned)ll[wi][4]|((unsigned)ll[wi][5]<<16); ul.w=(unsigned)ll[wi][6]|((unsigned)ll[wi][7]<<16);
            *(uint4*)(Bh + wid*8) = uh;
            *(uint4*)(Bl + wid*8) = ul;
        }
#pragma unroll
        for (int e=0;e<2;++e){
            int id = tid*2+e;
            int row = id>>5, k = id&31;
            unsigned short hs = f2bf(av[e]);
            unsigned short ls = f2bf(av[e] - bf2f(hs));
            int ai = ((k>>3)*16 + row)*8 + (k&7);
            Ah[ai] = hs; Al[ai] = ls;
        }
        __syncthreads();
        const int fa = (lg*16 + lm)*8;
        bf16x8 fah = *(const bf16x8*)(Ah + fa);
        bf16x8 fal = *(const bf16x8*)(Al + fa);
#pragma unroll
        for (int i=0;i<2;++i){
            int nt = w*2 + i;
            const int fb = (nt*64 + lg*16 + lm)*8;
            bf16x8 fbh = *(const bf16x8*)(Bh + fb);
            bf16x8 fbl = *(const bf16x8*)(Bl + fb);
            acc[i] = __builtin_amdgcn_mfma_f32_16x16x32_bf16(fah, fbh, acc[i], 0,0,0);
            acc[i] = __builtin_amdgcn_mfma_f32_16x16x32_bf16(fal, fbh, acc[i], 0,0,0);
            acc[i] = __builtin_amdgcn_mfma_f32_16x16x32_bf16(fah, fbl, acc[i], 0,0,0);
        }
        __syncthreads();
    }
#pragma unroll
    for (int i=0;i<2;++i){
        int nt = w*2 + i;
#pragma unroll
        for (int qq=0;qq<4;++qq){
            float val = acc[i][qq];
            int bb = bg*16 + lg*4 + qq;
            int k = h*128 + nt*16 + lm;
            unsigned short hv = f2bf(val);
            unsigned short lv = f2bf(val - bf2f(hv));
            size_t ui = (size_t)(k>>3)*512 + bb*8 + (k&7);
            Hi[ui] = hv; Lo[ui] = lv;
        }
    }
}

extern "C" void kernel_launch(void* const* d_in, const int* in_sizes, int n_in,
                              void* d_out, int out_size, void* d_ws, size_t ws_size,
                              hipStream_t stream)
{
    const float* hidden = (const float*)d_in[0];
    const float* cosb   = (const float*)d_in[1];
    const float* sinb   = (const float*)d_in[2];
    const float* kv     = (const float*)d_in[3];
    const float* w_q_a  = (const float*)d_in[4];
    const float* q_ln   = (const float*)d_in[5];
    const float* w_q_b  = (const float*)d_in[6];
    const float* w_kv_a = (const float*)d_in[7];
    const float* kv_ln  = (const float*)d_in[8];
    const float* w_uk_t = (const float*)d_in[9];
    const float* w_uv   = (const float*)d_in[10];
    const float* w_o    = (const float*)d_in[11];
    const int* slots    = (const int*)d_in[12];
    const int* seqlens  = (const int*)d_in[13];
    float* out = (float*)d_out;

    float* W = (float*)d_ws;
    float* P0     = W;                   // 4,194,304 f32 (wqa/wqb partials, attn Opart)
    float* P1     = W + 4194304;         // 2,097,152 (wkva partials, 28 splits = 1,032,192)
    float* query  = W + 6291456;         // 1,179,648
    float* latent = W + 7471104;         // 36,864
    float* Mp     = W + 7507968;         // 8,192
    float* Lp     = W + 7516160;         // 8,192
    unsigned short* pkq_h  = (unsigned short*)(W + 7524352);   // 131,072 f32 each
    unsigned short* pkq_l  = (unsigned short*)(W + 7655424);
    unsigned short* pkqc_h = (unsigned short*)(W + 7786496);   // 49,152 f32 each
    unsigned short* pkqc_l = (unsigned short*)(W + 7835648);
    unsigned short* pkao_h = (unsigned short*)(W + 7884800);   // 131,072 f32 each
    unsigned short* pkao_l = (unsigned short*)(W + 8015872);   // end 8,146,944

    // zero output for atomic accumulation (w_o GEMM)
    hipMemsetAsync(out, 0, (size_t)NB*HID*sizeof(float), stream);

    // hidden @ w_q_a (24 x 28 splits, ks=8) || hidden @ w_kv_a (9 x 28 splits, ks=8)
    hipLaunchKernelGGL(gemm_dual_raw, dim3(672+252), dim3(256), 0, stream,
                       hidden, HID, w_q_a, P0, 1536, 8, 24, 672, w_kv_a, P1, 576, 8, 9);
    hipLaunchKernelGGL(norm_dual, dim3(128), dim3(256), 0, stream,
                       P0, q_ln, pkqc_h, pkqc_l, 28, P1, kv_ln, cosb, sinb, latent, 28);
    hipLaunchKernelGGL(gemm_mfma, dim3(96,6), dim3(256), 0, stream, pkqc_h, pkqc_l, w_q_b, P0, 6144, 8);
    hipLaunchKernelGGL(finish_q, dim3(1536), dim3(256), 0, stream, P0, cosb, sinb, pkq_h, pkq_l, query, 6);
    hipLaunchKernelGGL(qlnope_mfma, dim3(32,4), dim3(256), 0, stream, pkq_h, pkq_l, w_uk_t, query);
    hipLaunchKernelGGL(attn_mfma, dim3(NSPLIT,64), dim3(512), 0, stream,
                       query, kv, latent, slots, seqlens, P0, Mp, Lp);
    hipLaunchKernelGGL(av_uv_merge, dim3(32,4), dim3(256), 0, stream, P0, Mp, Lp, w_uv, pkao_h, pkao_l);
    hipLaunchKernelGGL(gemm_atomic, dim3(112,8), dim3(256), 0, stream, pkao_h, pkao_l, w_o, out, 7168, 16);
}